// Round 7
// baseline (1386.256 us; speedup 1.0000x reference)
//
#include <hip/hip_runtime.h>
#include <hip/hip_bf16.h>

#define HH 64      // hidden
#define TT 256     // seq len
#define NB 1024    // batch
#define GG 256     // 4*H gates
#define DD0 5      // layer-0 input dim
#define DD1 128    // layer-1 input dim (2*H)

typedef __attribute__((ext_vector_type(8))) short bf16x8;  // 8 bf16 = 4 VGPR
typedef __attribute__((ext_vector_type(4))) float f32x4;   // MFMA C/D frag

#define MFMA16(a, b, c) __builtin_amdgcn_mfma_f32_16x16x32_bf16((a), (b), (c), 0, 0, 0)

__device__ __forceinline__ float sigf(float x) { return 1.0f / (1.0f + __expf(-x)); }
__device__ __forceinline__ float tanh_fast(float x) { return 2.0f / (1.0f + __expf(-2.0f * x)) - 1.0f; }

__device__ __forceinline__ float bf2f(short s) {
    unsigned int u = ((unsigned int)(unsigned short)s) << 16;
    return __builtin_bit_cast(float, u);
}
__device__ __forceinline__ short f2bf_rne(float x) {
    unsigned int u = __builtin_bit_cast(unsigned int, x);
    u += 0x7fffu + ((u >> 16) & 1u);  // round-to-nearest-even
    return (short)(u >> 16);
}

// Opaque pins: compiler cannot rematerialize an asm result, so the value must
// stay VGPR-resident across the recurrence (safe now: reg budget < cap 256;
// round-3's failure was the 128-reg cap forcing scratch spills).
__device__ __forceinline__ void pin(bf16x8& v) { asm volatile("" : "+v"(v)); }
__device__ __forceinline__ void pin(float& v)  { asm volatile("" : "+v"(v)); }

// Lane-linear A-fragment store for h (conflict-free ds_read_b128):
// reader lane l, seg s reads shorts [s*512 + l*8, +8) == h[row=l&15][k=s*32+8*(l>>4)+e].
__device__ __forceinline__ int hsf_waddr(int u, int row) {
    return ((u >> 5) * 512) + (((u >> 3) & 3) * 128) + row * 8 + (u & 7);  // lo plane: +1024
}

// out0 layout: u32[b][t][128 units] = bf16 hi (low16) | bf16 lo (high16).
// unit 0..63 = fwd, 64..127 = bwd.

// ---------------------------------------------------------------------------
// Layer 0, MFMA recurrence. 512 blocks = 256 row-quads x 2 dirs, 2 blocks/CU.
// Wave w owns n-tile quad {w,w+4,w+8,w+12}; lane (rg==0, col) holds i,f,g,o
// of unit u = 16w+col for rows 0..3. Weights PINNED in VGPRs.
// ---------------------------------------------------------------------------
__launch_bounds__(256, 2)
__global__ void lstm_l0(const float* __restrict__ x,
                        const float* __restrict__ w_ih_f, const float* __restrict__ w_hh_f,
                        const float* __restrict__ b_ih_f, const float* __restrict__ b_hh_f,
                        const float* __restrict__ w_ih_r, const float* __restrict__ w_hh_r,
                        const float* __restrict__ b_ih_r, const float* __restrict__ b_hh_r,
                        unsigned int* __restrict__ out0) {
    const int tid  = threadIdx.x;
    const int w    = tid >> 6;
    const int l    = tid & 63;
    const int col  = l & 15;
    const int rg   = l >> 4;
    const int dir  = blockIdx.x & 1;
    const int row0 = (blockIdx.x >> 1) * 4;
    const int u    = w * 16 + col;

    const float* w_ih = dir ? w_ih_r : w_ih_f;
    const float* w_hh = dir ? w_hh_r : w_hh_f;
    const float* b_ih = dir ? b_ih_r : b_ih_f;
    const float* b_hh = dir ? b_hh_r : b_hh_f;

    __shared__ __align__(16) float xs[4 * TT * DD0];  // 20 KB
    __shared__ __align__(16) short hsf[2][2048];      // 8 KB

    {   // stage x: 4 rows x 1280 contiguous floats
        const float4* src = (const float4*)(x + (size_t)row0 * TT * DD0);
        for (int i = tid; i < 4 * TT * DD0 / 4; i += 256) ((float4*)xs)[i] = src[i];
    }
    for (int i = tid; i < 2 * 2048; i += 256) ((short*)hsf)[i] = 0;

    bf16x8 whh_hi[4][2], whh_lo[4][2];
#pragma unroll
    for (int q = 0; q < 4; ++q) {
        const int gate = (w + 4 * q) * 16 + col;
#pragma unroll
        for (int ks = 0; ks < 2; ++ks) {
            const float* src = w_hh + gate * HH + ks * 32 + 8 * rg;
#pragma unroll
            for (int e = 0; e < 8; ++e) {
                float v = src[e];
                short h16 = f2bf_rne(v);
                whh_hi[q][ks][e] = h16;
                whh_lo[q][ks][e] = f2bf_rne(v - bf2f(h16));
            }
            pin(whh_hi[q][ks]);
            pin(whh_lo[q][ks]);
        }
    }
    float wxi[4][DD0], bb[4];
#pragma unroll
    for (int gi = 0; gi < 4; ++gi) {
        const int gate = u + 64 * gi;
#pragma unroll
        for (int d = 0; d < DD0; ++d) { wxi[gi][d] = w_ih[gate * DD0 + d]; pin(wxi[gi][d]); }
        bb[gi] = b_ih[gate] + b_hh[gate];
        pin(bb[gi]);
    }

    f32x4 cc = {0.f, 0.f, 0.f, 0.f};
    __syncthreads();

    for (int t = 0; t < TT; ++t) {
        const int tt  = dir ? (TT - 1 - t) : t;
        const int cur = t & 1, nxt = cur ^ 1;
        const short* hb = &hsf[cur][0];
        bf16x8 ah0 = *(const bf16x8*)&hb[0 * 512 + l * 8];  // h_hi k 0..31
        bf16x8 ah1 = *(const bf16x8*)&hb[1 * 512 + l * 8];  // h_hi k 32..63
        bf16x8 ah2 = *(const bf16x8*)&hb[2 * 512 + l * 8];  // h_lo k 0..31
        bf16x8 ah3 = *(const bf16x8*)&hb[3 * 512 + l * 8];  // h_lo k 32..63
        f32x4 acc[4];
#pragma unroll
        for (int q = 0; q < 4; ++q) {
            f32x4 a = {0.f, 0.f, 0.f, 0.f};
            a = MFMA16(ah0, whh_hi[q][0], a);
            a = MFMA16(ah1, whh_hi[q][1], a);
            a = MFMA16(ah2, whh_hi[q][0], a);   // h_lo * w_hi
            a = MFMA16(ah3, whh_hi[q][1], a);
            a = MFMA16(ah0, whh_lo[q][0], a);   // h_hi * w_lo
            a = MFMA16(ah1, whh_lo[q][1], a);
            acc[q] = a;
        }
        if (rg == 0) {
#pragma unroll
            for (int r = 0; r < 4; ++r) {
                const float* xr = &xs[r * TT * DD0 + tt * DD0];
                const float xv0 = xr[0], xv1 = xr[1], xv2 = xr[2], xv3 = xr[3], xv4 = xr[4];
                float g4[4];
#pragma unroll
                for (int gi = 0; gi < 4; ++gi)
                    g4[gi] = acc[gi][r] + bb[gi]
                           + wxi[gi][0] * xv0 + wxi[gi][1] * xv1 + wxi[gi][2] * xv2
                           + wxi[gi][3] * xv3 + wxi[gi][4] * xv4;
                const float cn = sigf(g4[1]) * cc[r] + sigf(g4[0]) * tanh_fast(g4[2]);
                const float hn = sigf(g4[3]) * tanh_fast(cn);
                cc[r] = cn;
                const short hi16 = f2bf_rne(hn);
                const short lo16 = f2bf_rne(hn - bf2f(hi16));
                const int wa = hsf_waddr(u, r);
                hsf[nxt][wa]        = hi16;
                hsf[nxt][wa + 1024] = lo16;
                out0[((size_t)(row0 + r) * TT + tt) * 128 + dir * 64 + u] =
                    (unsigned int)(unsigned short)hi16 | ((unsigned int)(unsigned short)lo16 << 16);
            }
        }
        __syncthreads();
    }
}

// ---------------------------------------------------------------------------
// xg chunk: xg[b*CH + tc][g] = h[b][t0+tc] @ W_ih1^T for tc in [0, CH).
// grid = NB*CH/16 blocks x 1024 threads; split-bf16 3-combo, f32 out.
// ---------------------------------------------------------------------------
__launch_bounds__(1024, 2)
__global__ void xg_gemm(const unsigned int* __restrict__ h,
                        const float* __restrict__ w1,
                        float* __restrict__ xg, int t0, int CH) {
    const int tid = threadIdx.x;
    const int nt  = tid >> 6;
    const int l   = tid & 63;
    const int col = l & 15;
    const int rg  = l >> 4;
    const int m0  = blockIdx.x * 16;
    const int b   = m0 / CH;
    const int tc  = m0 - b * CH;   // CH multiple of 16 -> whole tile same b

    bf16x8 wh[4], wl[4];
    const int gate = nt * 16 + col;
#pragma unroll
    for (int ks = 0; ks < 4; ++ks) {
        const float* src = w1 + gate * DD1 + ks * 32 + 8 * rg;
#pragma unroll
        for (int e = 0; e < 8; ++e) {
            float v = src[e];
            short h16 = f2bf_rne(v);
            wh[ks][e] = h16;
            wl[ks][e] = f2bf_rne(v - bf2f(h16));
        }
    }

    const unsigned int* ap = h + ((size_t)b * TT + t0 + tc + col) * 128 + 8 * rg;
    bf16x8 ah[4], al[4];
#pragma unroll
    for (int ks = 0; ks < 4; ++ks) {
        const uint4 p0 = *(const uint4*)&ap[ks * 32];
        const uint4 p1 = *(const uint4*)&ap[ks * 32 + 4];
        const unsigned int pp[8] = {p0.x, p0.y, p0.z, p0.w, p1.x, p1.y, p1.z, p1.w};
#pragma unroll
        for (int e = 0; e < 8; ++e) {
            ah[ks][e] = (short)(pp[e] & 0xffffu);
            al[ks][e] = (short)(pp[e] >> 16);
        }
    }
    f32x4 a = {0.f, 0.f, 0.f, 0.f};
#pragma unroll
    for (int ks = 0; ks < 4; ++ks) {
        a = MFMA16(ah[ks], wh[ks], a);
        a = MFMA16(al[ks], wh[ks], a);
        a = MFMA16(ah[ks], wl[ks], a);
    }
#pragma unroll
    for (int j = 0; j < 4; ++j)
        xg[(size_t)(m0 + rg * 4 + j) * GG + nt * 16 + col] = a[j];
}

// ---------------------------------------------------------------------------
// Layer 1 forward, LEAN chunk: gates = xg[row*CH + t] + h @ W_hh^T + bias over
// t in [0, CH); (h, c) state carried across chunk launches. 512 blocks x 2 rows.
// ---------------------------------------------------------------------------
__launch_bounds__(256, 2)
__global__ void lstm_l1_lean(const float* __restrict__ xg,
                             const float* __restrict__ w_hh,
                             const float* __restrict__ b_ih, const float* __restrict__ b_hh,
                             float* __restrict__ c_state, float* __restrict__ h_state,
                             float* __restrict__ h_last,
                             int CH, int first, int last) {
    const int tid  = threadIdx.x;
    const int w    = tid >> 6;
    const int l    = tid & 63;
    const int col  = l & 15;
    const int rg   = l >> 4;
    const int row0 = blockIdx.x * 2;
    const int u    = w * 16 + col;

    __shared__ __align__(16) short hsf[2][2048];     // 8 KB
    __shared__ __align__(16) float xgs[2][2 * GG];   // 4 KB double buffer

    for (int i = tid; i < 2 * 2048; i += 256) ((short*)hsf)[i] = 0;

    bf16x8 whh_hi[4][2], whh_lo[4][2];
#pragma unroll
    for (int q = 0; q < 4; ++q) {
        const int gate = (w + 4 * q) * 16 + col;
#pragma unroll
        for (int ks = 0; ks < 2; ++ks) {
            const float* src = w_hh + gate * HH + ks * 32 + 8 * rg;
#pragma unroll
            for (int e = 0; e < 8; ++e) {
                float v = src[e];
                short h16 = f2bf_rne(v);
                whh_hi[q][ks][e] = h16;
                whh_lo[q][ks][e] = f2bf_rne(v - bf2f(h16));
            }
            pin(whh_hi[q][ks]);
            pin(whh_lo[q][ks]);
        }
    }
    float bb[4];
#pragma unroll
    for (int gi = 0; gi < 4; ++gi) { bb[gi] = b_ih[u + 64 * gi] + b_hh[u + 64 * gi]; pin(bb[gi]); }

    float cc[2] = {0.f, 0.f};
    __syncthreads();  // hsf zero-init done before state overwrite

    if (!first && rg == 0) {
#pragma unroll
        for (int r = 0; r < 2; ++r) {
            cc[r] = c_state[(size_t)(row0 + r) * HH + u];
            const float hv = h_state[(size_t)(row0 + r) * HH + u];
            const short hi16 = f2bf_rne(hv);
            const int wa = hsf_waddr(u, r);
            hsf[0][wa]        = hi16;
            hsf[0][wa + 1024] = f2bf_rne(hv - bf2f(hi16));
        }
    }

    const int prow = tid >> 7, pj = tid & 127;  // xg prefetch assignment
    {   // preload t = 0
        const float2 v = *(const float2*)&xg[((size_t)(row0 + prow) * CH + 0) * GG + pj * 2];
        *(float2*)&xgs[0][prow * GG + pj * 2] = v;
    }
    __syncthreads();

    for (int t = 0; t < CH; ++t) {
        const int cur = t & 1, nxt = cur ^ 1;
        float2 pf;
        if (t + 1 < CH)
            pf = *(const float2*)&xg[((size_t)(row0 + prow) * CH + (t + 1)) * GG + pj * 2];

        const short* hb = &hsf[cur][0];
        bf16x8 ah0 = *(const bf16x8*)&hb[0 * 512 + l * 8];
        bf16x8 ah1 = *(const bf16x8*)&hb[1 * 512 + l * 8];
        bf16x8 ah2 = *(const bf16x8*)&hb[2 * 512 + l * 8];
        bf16x8 ah3 = *(const bf16x8*)&hb[3 * 512 + l * 8];
        f32x4 acc[4];
#pragma unroll
        for (int q = 0; q < 4; ++q) {
            f32x4 a = {0.f, 0.f, 0.f, 0.f};
            a = MFMA16(ah0, whh_hi[q][0], a);
            a = MFMA16(ah1, whh_hi[q][1], a);
            a = MFMA16(ah2, whh_hi[q][0], a);
            a = MFMA16(ah3, whh_hi[q][1], a);
            a = MFMA16(ah0, whh_lo[q][0], a);
            a = MFMA16(ah1, whh_lo[q][1], a);
            acc[q] = a;
        }
        if (rg == 0) {
#pragma unroll
            for (int r = 0; r < 2; ++r) {
                float g4[4];
#pragma unroll
                for (int gi = 0; gi < 4; ++gi)
                    g4[gi] = acc[gi][r] + xgs[cur][r * GG + u + 64 * gi] + bb[gi];
                const float cn = sigf(g4[1]) * cc[r] + sigf(g4[0]) * tanh_fast(g4[2]);
                const float hn = sigf(g4[3]) * tanh_fast(cn);
                cc[r] = cn;
                const short hi16 = f2bf_rne(hn);
                const int wa = hsf_waddr(u, r);
                hsf[nxt][wa]        = hi16;
                hsf[nxt][wa + 1024] = f2bf_rne(hn - bf2f(hi16));
                if (t == CH - 1) {
                    c_state[(size_t)(row0 + r) * HH + u] = cn;
                    h_state[(size_t)(row0 + r) * HH + u] = hn;
                    if (last) h_last[(size_t)(row0 + r) * HH + u] = hn;
                }
            }
        }
        if (t + 1 < CH) *(float2*)&xgs[nxt][prow * GG + pj * 2] = pf;
        __syncthreads();
    }
}

// ---------------------------------------------------------------------------
// Layer 1 forward, FUSED fallback (ws too small for any xg chunk).
// 256 blocks x 4 rows (all CUs busy; round-6 had 128 blocks = half chip idle).
// ---------------------------------------------------------------------------
__launch_bounds__(256, 1)
__global__ void lstm_l1_fused(const unsigned int* __restrict__ in0,
                              const float* __restrict__ w_ih, const float* __restrict__ w_hh,
                              const float* __restrict__ b_ih, const float* __restrict__ b_hh,
                              float* __restrict__ h_last) {
    const int tid  = threadIdx.x;
    const int w    = tid >> 6;
    const int l    = tid & 63;
    const int col  = l & 15;
    const int rg   = l >> 4;
    const int row0 = blockIdx.x * 4;
    const int u    = w * 16 + col;

    __shared__ __align__(16) short sh_wf[128][64 * 8];  // 128 KB W_ih hi/lo frags
    __shared__ __align__(16) short hs[2][16][136];

    for (int i = tid; i < 2 * 16 * 136; i += 256) ((short*)hs)[i] = 0;

    for (int it = 0; it < 16; ++it) {
        const int fih = w * 16 + it;
        const int nt = fih >> 2, ks = fih & 3;
        const float* src = w_ih + (nt * 16 + col) * DD1 + ks * 32 + 8 * rg;
        bf16x8 hi, lo;
#pragma unroll
        for (int e = 0; e < 8; ++e) {
            float v = src[e];
            short h16 = f2bf_rne(v);
            hi[e] = h16;
            lo[e] = f2bf_rne(v - bf2f(h16));
        }
        *(bf16x8*)&sh_wf[nt * 8 + ks][l * 8]     = hi;
        *(bf16x8*)&sh_wf[nt * 8 + 4 + ks][l * 8] = lo;
    }

    bf16x8 whh_hi[4][2], whh_lo[4][2];
#pragma unroll
    for (int q = 0; q < 4; ++q) {
        const int gate = (w + 4 * q) * 16 + col;
#pragma unroll
        for (int ks = 0; ks < 2; ++ks) {
            const float* src = w_hh + gate * HH + ks * 32 + 8 * rg;
#pragma unroll
            for (int e = 0; e < 8; ++e) {
                float v = src[e];
                short h16 = f2bf_rne(v);
                whh_hi[q][ks][e] = h16;
                whh_lo[q][ks][e] = f2bf_rne(v - bf2f(h16));
            }
            pin(whh_hi[q][ks]);
            pin(whh_lo[q][ks]);
        }
    }
    float bb[4];
#pragma unroll
    for (int gi = 0; gi < 4; ++gi) { bb[gi] = b_ih[u + 64 * gi] + b_hh[u + 64 * gi]; pin(bb[gi]); }

    const int arow = row0 + (col < 4 ? col : 3);
    const unsigned int* xsrc = in0 + (size_t)arow * TT * 128 + 8 * rg;

    f32x4 c = {0.f, 0.f, 0.f, 0.f};
    bf16x8 xA[8], xB[8];

    auto loadx = [&](int t, bf16x8 (&xr)[8]) {
        const unsigned int* p = xsrc + (size_t)t * 128;
#pragma unroll
        for (int ks = 0; ks < 4; ++ks) {
            const uint4 p0 = *(const uint4*)&p[ks * 32];
            const uint4 p1 = *(const uint4*)&p[ks * 32 + 4];
            const unsigned int pp[8] = {p0.x, p0.y, p0.z, p0.w, p1.x, p1.y, p1.z, p1.w};
#pragma unroll
            for (int e = 0; e < 8; ++e) {
                xr[ks][e]     = (short)(pp[e] & 0xffffu);
                xr[4 + ks][e] = (short)(pp[e] >> 16);
            }
        }
    };

    auto step = [&](int t, const bf16x8 (&xr)[8]) {
        const int cur = t & 1;
        const short* hrow = &hs[cur][col][0];
        bf16x8 ah0 = *(const bf16x8*)&hrow[ 0 + 8 * rg];
        bf16x8 ah1 = *(const bf16x8*)&hrow[32 + 8 * rg];
        bf16x8 ah2 = *(const bf16x8*)&hrow[64 + 8 * rg];
        bf16x8 ah3 = *(const bf16x8*)&hrow[96 + 8 * rg];
        f32x4 acc[4];
#pragma unroll
        for (int q = 0; q < 4; ++q) {
            const int nt = w + 4 * q;
            f32x4 a = {0.f, 0.f, 0.f, 0.f};
            a = MFMA16(ah0, whh_hi[q][0], a);
            a = MFMA16(ah1, whh_hi[q][1], a);
            a = MFMA16(ah2, whh_hi[q][0], a);
            a = MFMA16(ah3, whh_hi[q][1], a);
            a = MFMA16(ah0, whh_lo[q][0], a);
            a = MFMA16(ah1, whh_lo[q][1], a);
#pragma unroll
            for (int ks = 0; ks < 4; ++ks) {
                bf16x8 wh = *(const bf16x8*)&sh_wf[nt * 8 + ks][l * 8];
                bf16x8 wl = *(const bf16x8*)&sh_wf[nt * 8 + 4 + ks][l * 8];
                a = MFMA16(xr[ks], wh, a);
                a = MFMA16(xr[4 + ks], wh, a);
                a = MFMA16(xr[ks], wl, a);
            }
            acc[q] = a;
        }
        if (rg == 0) {
            const int nxt = cur ^ 1;
#pragma unroll
            for (int r = 0; r < 4; ++r) {
                const float gi_ = acc[0][r] + bb[0];
                const float gf_ = acc[1][r] + bb[1];
                const float gg_ = acc[2][r] + bb[2];
                const float go_ = acc[3][r] + bb[3];
                const float cn = sigf(gf_) * c[r] + sigf(gi_) * tanh_fast(gg_);
                const float hn = sigf(go_) * tanh_fast(cn);
                c[r] = cn;
                const short hi16 = f2bf_rne(hn);
                hs[nxt][r][u]      = hi16;
                hs[nxt][r][64 + u] = f2bf_rne(hn - bf2f(hi16));
                if (t == TT - 1) h_last[(size_t)(row0 + r) * HH + u] = hn;
            }
        }
        __syncthreads();
    };

    loadx(0, xA);
    __syncthreads();
    for (int t = 0; t < TT; t += 2) {
        loadx(t + 1, xB);
        step(t, xA);
        if (t + 2 < TT) loadx(t + 2, xA);
        step(t + 1, xB);
    }
}

// ---------------------------------------------------------------------------
// Tail: layer-1 backward is ONE step at t=T-1 from zero state (h0=0 kills the
// w_hh term), then FC. 1024 blocks, 256 threads.
// ---------------------------------------------------------------------------
__global__ void lstm_tail(const unsigned int* __restrict__ in0,
                          const float* __restrict__ h1f,
                          const float* __restrict__ w_ih_r,
                          const float* __restrict__ b_ih_r, const float* __restrict__ b_hh_r,
                          const float* __restrict__ fc_w, const float* __restrict__ fc_b,
                          float* __restrict__ out) {
    const int b   = blockIdx.x;
    const int tid = threadIdx.x;
    __shared__ __align__(16) float insl[DD1];
    __shared__ __align__(16) float hb[HH];
    __shared__ __align__(16) float gsh[256];

    if (tid < DD1) {
        const unsigned int v = in0[((size_t)b * TT + (TT - 1)) * 128 + tid];
        insl[tid] = bf2f((short)(v & 0xffffu)) + bf2f((short)(v >> 16));
    }
    __syncthreads();

    float a0 = b_ih_r[tid] + b_hh_r[tid], a1 = 0.f, a2 = 0.f, a3 = 0.f;
    const float4* in4 = (const float4*)insl;
#pragma unroll
    for (int kk = 0; kk < 32; ++kk) {
        float4 iv = in4[kk];
        float4 wv = *(const float4*)&w_ih_r[tid * DD1 + 4 * kk];
        a0 += wv.x * iv.x;
        a1 += wv.y * iv.y;
        a2 += wv.z * iv.z;
        a3 += wv.w * iv.w;
    }
    gsh[tid] = (a0 + a1) + (a2 + a3);
    __syncthreads();

    if (tid < HH) {
        const float gi = gsh[tid], gc = gsh[tid + 128], go = gsh[tid + 192];
        const float ccv = sigf(gi) * tanh_fast(gc);  // c_prev = 0
        hb[tid] = sigf(go) * tanh_fast(ccv);
    }
    __syncthreads();

    if (tid < 64) {
        float p = fc_w[tid] * h1f[(size_t)b * HH + tid] + fc_w[HH + tid] * hb[tid];
#pragma unroll
        for (int off = 32; off; off >>= 1) p += __shfl_xor(p, off);
        if (tid == 0) out[b] = p + fc_b[0];
    }
}

// ---------------------------------------------------------------------------
extern "C" void kernel_launch(void* const* d_in, const int* in_sizes, int n_in,
                              void* d_out, int out_size, void* d_ws, size_t ws_size,
                              hipStream_t stream) {
    const float* x = (const float*)d_in[0];
    // l0 fwd: 1..4, l0 rev: 5..8, l1 fwd: 9..12, l1 rev: 13..16, fc: 17,18
    char* ws = (char*)d_ws;
    const size_t out0_b = (size_t)NB * TT * 128 * 4;   // 134.2 MB (u32 hi|lo)
    const size_t h1f_b  = (size_t)NB * HH * 4;         // 256 KB
    const size_t st_b   = (size_t)NB * HH * 4;         // per state array
    const size_t fixed  = out0_b + h1f_b + 2 * st_b;

    unsigned int* out0 = (unsigned int*)ws;
    float* h1f     = (float*)(ws + out0_b);
    float* c_state = (float*)(ws + out0_b + h1f_b);
    float* h_state = (float*)(ws + out0_b + h1f_b + st_b);
    float* xg      = (float*)(ws + fixed);

    int CH = 0;
    for (int c = TT; c >= 64; c >>= 1)
        if (ws_size >= fixed + (size_t)NB * c * GG * 4) { CH = c; break; }

    lstm_l0<<<512, 256, 0, stream>>>(
        x, (const float*)d_in[1], (const float*)d_in[2], (const float*)d_in[3], (const float*)d_in[4],
        (const float*)d_in[5], (const float*)d_in[6], (const float*)d_in[7], (const float*)d_in[8], out0);

    if (CH > 0) {
        const int nc = TT / CH;
        for (int k = 0; k < nc; ++k) {
            xg_gemm<<<NB * CH / 16, 1024, 0, stream>>>(
                out0, (const float*)d_in[9], xg, k * CH, CH);
            lstm_l1_lean<<<512, 256, 0, stream>>>(
                xg, (const float*)d_in[10], (const float*)d_in[11], (const float*)d_in[12],
                c_state, h_state, h1f, CH, k == 0 ? 1 : 0, k == nc - 1 ? 1 : 0);
        }
    } else {
        lstm_l1_fused<<<256, 256, 0, stream>>>(
            out0, (const float*)d_in[9], (const float*)d_in[10], (const float*)d_in[11],
            (const float*)d_in[12], h1f);
    }
    lstm_tail<<<1024, 256, 0, stream>>>(
        out0, h1f, (const float*)d_in[13], (const float*)d_in[15], (const float*)d_in[16],
        (const float*)d_in[17], (const float*)d_in[18], (float*)d_out);
}

// Round 8
// 760.900 us; speedup vs baseline: 1.8219x; 1.8219x over previous
//
#include <hip/hip_runtime.h>
#include <hip/hip_bf16.h>

#define HH 64      // hidden
#define TT 256     // seq len
#define NB 1024    // batch
#define GG 256     // 4*H gates
#define DD0 5      // layer-0 input dim
#define DD1 128    // layer-1 input dim (2*H)

typedef __attribute__((ext_vector_type(8))) short bf16x8;  // 8 bf16 = 4 VGPR
typedef __attribute__((ext_vector_type(4))) float f32x4;   // MFMA C/D frag

#define MFMA16(a, b, c) __builtin_amdgcn_mfma_f32_16x16x32_bf16((a), (b), (c), 0, 0, 0)

// v_rcp_f32: 1 trans-pipe op instead of the ~11-instr IEEE division sequence
// the compiler emits for 1.0f/x without fast-math (round-7 lesson: those
// divisions were ~40% of the recurrence's VALU issue).
__device__ __forceinline__ float rcp_fast(float x) {
    float r;
    asm("v_rcp_f32 %0, %1" : "=v"(r) : "v"(x));
    return r;
}
__device__ __forceinline__ float sigf(float x) { return rcp_fast(1.0f + __expf(-x)); }
__device__ __forceinline__ float tanh_fast(float x) { return 2.0f * rcp_fast(1.0f + __expf(-2.0f * x)) - 1.0f; }

__device__ __forceinline__ float bf2f(short s) {
    unsigned int u = ((unsigned int)(unsigned short)s) << 16;
    return __builtin_bit_cast(float, u);
}
__device__ __forceinline__ short f2bf_rne(float x) {
    unsigned int u = __builtin_bit_cast(unsigned int, x);
    u += 0x7fffu + ((u >> 16) & 1u);  // round-to-nearest-even
    return (short)(u >> 16);
}

// Lane-linear A-fragment store for h (conflict-free ds_read_b128):
// reader lane l, seg s reads shorts [s*512 + l*8, +8) == h[row=l&15][k=s*32+8*(l>>4)+e].
__device__ __forceinline__ int hsf_waddr(int u, int row) {
    return ((u >> 5) * 512) + (((u >> 3) & 3) * 128) + row * 8 + (u & 7);  // lo plane: +1024
}

// out0 layout: u32[b][t][128 units] = bf16 hi (low16) | bf16 lo (high16).
// unit 0..63 = fwd, 64..127 = bwd.

// ---------------------------------------------------------------------------
// Layer 0, MFMA recurrence. 256 blocks = 128 row-octets x 2 dirs, 1 block/CU.
// (Round-7 lesson: every wave pays the full exec-masked update stream, so
// fewer blocks x more rows/block = same useful work at half the VALU issue.)
// Wave w owns n-tile quad {w,w+4,w+8,w+12}; lanes rg<2 update rows rg*4+r.
// ---------------------------------------------------------------------------
__launch_bounds__(256, 1)
__global__ void lstm_l0(const float* __restrict__ x,
                        const float* __restrict__ w_ih_f, const float* __restrict__ w_hh_f,
                        const float* __restrict__ b_ih_f, const float* __restrict__ b_hh_f,
                        const float* __restrict__ w_ih_r, const float* __restrict__ w_hh_r,
                        const float* __restrict__ b_ih_r, const float* __restrict__ b_hh_r,
                        unsigned int* __restrict__ out0) {
    const int tid  = threadIdx.x;
    const int w    = tid >> 6;
    const int l    = tid & 63;
    const int col  = l & 15;
    const int rg   = l >> 4;
    const int dir  = blockIdx.x & 1;
    const int row0 = (blockIdx.x >> 1) * 8;
    const int u    = w * 16 + col;

    const float* w_ih = dir ? w_ih_r : w_ih_f;
    const float* w_hh = dir ? w_hh_r : w_hh_f;
    const float* b_ih = dir ? b_ih_r : b_ih_f;
    const float* b_hh = dir ? b_hh_r : b_hh_f;

    __shared__ __align__(16) float xs[8 * TT * DD0];  // 40 KB
    __shared__ __align__(16) short hsf[2][2048];      // 8 KB

    {   // stage x: 8 rows x 1280 contiguous floats
        const float4* src = (const float4*)(x + (size_t)row0 * TT * DD0);
        for (int i = tid; i < 8 * TT * DD0 / 4; i += 256) ((float4*)xs)[i] = src[i];
    }
    for (int i = tid; i < 2 * 2048; i += 256) ((short*)hsf)[i] = 0;

    bf16x8 whh_hi[4][2], whh_lo[4][2];
#pragma unroll
    for (int q = 0; q < 4; ++q) {
        const int gate = (w + 4 * q) * 16 + col;
#pragma unroll
        for (int ks = 0; ks < 2; ++ks) {
            const float* src = w_hh + gate * HH + ks * 32 + 8 * rg;
#pragma unroll
            for (int e = 0; e < 8; ++e) {
                float v = src[e];
                short h16 = f2bf_rne(v);
                whh_hi[q][ks][e] = h16;
                whh_lo[q][ks][e] = f2bf_rne(v - bf2f(h16));
            }
        }
    }
    float wxi[4][DD0], bb[4];
#pragma unroll
    for (int gi = 0; gi < 4; ++gi) {
        const int gate = u + 64 * gi;
#pragma unroll
        for (int d = 0; d < DD0; ++d) wxi[gi][d] = w_ih[gate * DD0 + d];
        bb[gi] = b_ih[gate] + b_hh[gate];
    }

    f32x4 cc = {0.f, 0.f, 0.f, 0.f};
    __syncthreads();

    for (int t = 0; t < TT; ++t) {
        const int tt  = dir ? (TT - 1 - t) : t;
        const int cur = t & 1, nxt = cur ^ 1;
        const short* hb = &hsf[cur][0];
        bf16x8 ah0 = *(const bf16x8*)&hb[0 * 512 + l * 8];  // h_hi k 0..31
        bf16x8 ah1 = *(const bf16x8*)&hb[1 * 512 + l * 8];  // h_hi k 32..63
        bf16x8 ah2 = *(const bf16x8*)&hb[2 * 512 + l * 8];  // h_lo k 0..31
        bf16x8 ah3 = *(const bf16x8*)&hb[3 * 512 + l * 8];  // h_lo k 32..63
        f32x4 acc[4];
#pragma unroll
        for (int q = 0; q < 4; ++q) {
            f32x4 a = {0.f, 0.f, 0.f, 0.f};
            a = MFMA16(ah0, whh_hi[q][0], a);
            a = MFMA16(ah1, whh_hi[q][1], a);
            a = MFMA16(ah2, whh_hi[q][0], a);   // h_lo * w_hi
            a = MFMA16(ah3, whh_hi[q][1], a);
            a = MFMA16(ah0, whh_lo[q][0], a);   // h_hi * w_lo
            a = MFMA16(ah1, whh_lo[q][1], a);
            acc[q] = a;
        }
        if (rg < 2) {
#pragma unroll
            for (int r = 0; r < 4; ++r) {
                const int row = rg * 4 + r;
                const float* xr = &xs[row * TT * DD0 + tt * DD0];
                const float xv0 = xr[0], xv1 = xr[1], xv2 = xr[2], xv3 = xr[3], xv4 = xr[4];
                float g4[4];
#pragma unroll
                for (int gi = 0; gi < 4; ++gi)
                    g4[gi] = acc[gi][r] + bb[gi]
                           + wxi[gi][0] * xv0 + wxi[gi][1] * xv1 + wxi[gi][2] * xv2
                           + wxi[gi][3] * xv3 + wxi[gi][4] * xv4;
                const float cn = sigf(g4[1]) * cc[r] + sigf(g4[0]) * tanh_fast(g4[2]);
                const float hn = sigf(g4[3]) * tanh_fast(cn);
                cc[r] = cn;
                const short hi16 = f2bf_rne(hn);
                const short lo16 = f2bf_rne(hn - bf2f(hi16));
                const int wa = hsf_waddr(u, row);
                hsf[nxt][wa]        = hi16;
                hsf[nxt][wa + 1024] = lo16;
                out0[((size_t)(row0 + row) * TT + tt) * 128 + dir * 64 + u] =
                    (unsigned int)(unsigned short)hi16 | ((unsigned int)(unsigned short)lo16 << 16);
            }
        }
        __syncthreads();
    }
}

// ---------------------------------------------------------------------------
// Layer 1 forward, FUSED: gates = [x_t | h] @ [W_ih | W_hh]^T + bias.
// 256 blocks x 4 rows (1 block/CU, all CUs busy). W_ih hi/lo frags in LDS
// (128 KB); W_hh frags in regs; x A-frags prefetched 2 steps deep from
// global (HBM ~900 cy covered by ~1 step of compute). Only final h stored.
// ---------------------------------------------------------------------------
__launch_bounds__(256, 1)
__global__ void lstm_l1_fused(const unsigned int* __restrict__ in0,
                              const float* __restrict__ w_ih, const float* __restrict__ w_hh,
                              const float* __restrict__ b_ih, const float* __restrict__ b_hh,
                              float* __restrict__ h_last) {
    const int tid  = threadIdx.x;
    const int w    = tid >> 6;
    const int l    = tid & 63;
    const int col  = l & 15;
    const int rg   = l >> 4;
    const int row0 = blockIdx.x * 4;
    const int u    = w * 16 + col;

    __shared__ __align__(16) short sh_wf[128][64 * 8];  // 128 KB W_ih hi/lo frags
    __shared__ __align__(16) short hsf[2][2048];        // 8 KB

    for (int i = tid; i < 2 * 2048; i += 256) ((short*)hsf)[i] = 0;

    for (int it = 0; it < 16; ++it) {
        const int fih = w * 16 + it;
        const int nt = fih >> 2, ks = fih & 3;
        const float* src = w_ih + (nt * 16 + col) * DD1 + ks * 32 + 8 * rg;
        bf16x8 hi, lo;
#pragma unroll
        for (int e = 0; e < 8; ++e) {
            float v = src[e];
            short h16 = f2bf_rne(v);
            hi[e] = h16;
            lo[e] = f2bf_rne(v - bf2f(h16));
        }
        *(bf16x8*)&sh_wf[nt * 8 + ks][l * 8]     = hi;
        *(bf16x8*)&sh_wf[nt * 8 + 4 + ks][l * 8] = lo;
    }

    bf16x8 whh_hi[4][2], whh_lo[4][2];
#pragma unroll
    for (int q = 0; q < 4; ++q) {
        const int gate = (w + 4 * q) * 16 + col;
#pragma unroll
        for (int ks = 0; ks < 2; ++ks) {
            const float* src = w_hh + gate * HH + ks * 32 + 8 * rg;
#pragma unroll
            for (int e = 0; e < 8; ++e) {
                float v = src[e];
                short h16 = f2bf_rne(v);
                whh_hi[q][ks][e] = h16;
                whh_lo[q][ks][e] = f2bf_rne(v - bf2f(h16));
            }
        }
    }
    float bb[4];
#pragma unroll
    for (int gi = 0; gi < 4; ++gi) bb[gi] = b_ih[u + 64 * gi] + b_hh[u + 64 * gi];

    const int arow = row0 + (col < 4 ? col : 3);  // A rows 4..15 clamped (C rows unread)
    const unsigned int* xsrc = in0 + (size_t)arow * TT * 128 + 8 * rg;

    f32x4 c = {0.f, 0.f, 0.f, 0.f};
    bf16x8 xA[8], xB[8];

    auto loadx = [&](int t, bf16x8 (&xr)[8]) {
        const unsigned int* p = xsrc + (size_t)t * 128;
#pragma unroll
        for (int ks = 0; ks < 4; ++ks) {
            const uint4 p0 = *(const uint4*)&p[ks * 32];
            const uint4 p1 = *(const uint4*)&p[ks * 32 + 4];
            const unsigned int pp[8] = {p0.x, p0.y, p0.z, p0.w, p1.x, p1.y, p1.z, p1.w};
#pragma unroll
            for (int e = 0; e < 8; ++e) {
                xr[ks][e]     = (short)(pp[e] & 0xffffu);
                xr[4 + ks][e] = (short)(pp[e] >> 16);
            }
        }
    };

    auto step = [&](int t, const bf16x8 (&xr)[8]) {
        const int cur = t & 1;
        const short* hb = &hsf[cur][0];
        bf16x8 ah0 = *(const bf16x8*)&hb[0 * 512 + l * 8];
        bf16x8 ah1 = *(const bf16x8*)&hb[1 * 512 + l * 8];
        bf16x8 ah2 = *(const bf16x8*)&hb[2 * 512 + l * 8];
        bf16x8 ah3 = *(const bf16x8*)&hb[3 * 512 + l * 8];
        f32x4 acc[4];
#pragma unroll
        for (int q = 0; q < 4; ++q) {
            const int nt = w + 4 * q;
            f32x4 a = {0.f, 0.f, 0.f, 0.f};
            a = MFMA16(ah0, whh_hi[q][0], a);
            a = MFMA16(ah1, whh_hi[q][1], a);
            a = MFMA16(ah2, whh_hi[q][0], a);
            a = MFMA16(ah3, whh_hi[q][1], a);
            a = MFMA16(ah0, whh_lo[q][0], a);
            a = MFMA16(ah1, whh_lo[q][1], a);
#pragma unroll
            for (int ks = 0; ks < 4; ++ks) {
                bf16x8 wh = *(const bf16x8*)&sh_wf[nt * 8 + ks][l * 8];
                bf16x8 wl = *(const bf16x8*)&sh_wf[nt * 8 + 4 + ks][l * 8];
                a = MFMA16(xr[ks], wh, a);       // x_hi * w_hi
                a = MFMA16(xr[4 + ks], wh, a);   // x_lo * w_hi
                a = MFMA16(xr[ks], wl, a);       // x_hi * w_lo
            }
            acc[q] = a;
        }
        if (rg == 0) {
            const int nxt = cur ^ 1;
#pragma unroll
            for (int r = 0; r < 4; ++r) {
                const float gi_ = acc[0][r] + bb[0];
                const float gf_ = acc[1][r] + bb[1];
                const float gg_ = acc[2][r] + bb[2];
                const float go_ = acc[3][r] + bb[3];
                const float cn = sigf(gf_) * c[r] + sigf(gi_) * tanh_fast(gg_);
                const float hn = sigf(go_) * tanh_fast(cn);
                c[r] = cn;
                const short hi16 = f2bf_rne(hn);
                const int wa = hsf_waddr(u, r);
                hsf[nxt][wa]        = hi16;
                hsf[nxt][wa + 1024] = f2bf_rne(hn - bf2f(hi16));
                if (t == TT - 1) h_last[(size_t)(row0 + r) * HH + u] = hn;
            }
        }
        __syncthreads();
    };

    loadx(0, xA);
    loadx(1, xB);
    __syncthreads();
    for (int t = 0; t < TT; t += 2) {
        step(t, xA);
        if (t + 2 < TT) loadx(t + 2, xA);   // lands during step t+1 (~1 step cover)
        step(t + 1, xB);
        if (t + 3 < TT) loadx(t + 3, xB);
    }
}

// ---------------------------------------------------------------------------
// Tail: layer-1 backward is ONE step at t=T-1 from zero state (h0=0 kills the
// w_hh term), then FC. 1024 blocks, 256 threads.
// ---------------------------------------------------------------------------
__global__ void lstm_tail(const unsigned int* __restrict__ in0,
                          const float* __restrict__ h1f,
                          const float* __restrict__ w_ih_r,
                          const float* __restrict__ b_ih_r, const float* __restrict__ b_hh_r,
                          const float* __restrict__ fc_w, const float* __restrict__ fc_b,
                          float* __restrict__ out) {
    const int b   = blockIdx.x;
    const int tid = threadIdx.x;
    __shared__ __align__(16) float insl[DD1];
    __shared__ __align__(16) float hb[HH];
    __shared__ __align__(16) float gsh[256];

    if (tid < DD1) {
        const unsigned int v = in0[((size_t)b * TT + (TT - 1)) * 128 + tid];
        insl[tid] = bf2f((short)(v & 0xffffu)) + bf2f((short)(v >> 16));
    }
    __syncthreads();

    float a0 = b_ih_r[tid] + b_hh_r[tid], a1 = 0.f, a2 = 0.f, a3 = 0.f;
    const float4* in4 = (const float4*)insl;
#pragma unroll
    for (int kk = 0; kk < 32; ++kk) {
        float4 iv = in4[kk];
        float4 wv = *(const float4*)&w_ih_r[tid * DD1 + 4 * kk];
        a0 += wv.x * iv.x;
        a1 += wv.y * iv.y;
        a2 += wv.z * iv.z;
        a3 += wv.w * iv.w;
    }
    gsh[tid] = (a0 + a1) + (a2 + a3);
    __syncthreads();

    if (tid < HH) {
        const float gi = gsh[tid], gc = gsh[tid + 128], go = gsh[tid + 192];
        const float ccv = sigf(gi) * tanh_fast(gc);  // c_prev = 0
        hb[tid] = sigf(go) * tanh_fast(ccv);
    }
    __syncthreads();

    if (tid < 64) {
        float p = fc_w[tid] * h1f[(size_t)b * HH + tid] + fc_w[HH + tid] * hb[tid];
#pragma unroll
        for (int off = 32; off; off >>= 1) p += __shfl_xor(p, off);
        if (tid == 0) out[b] = p + fc_b[0];
    }
}

// ---------------------------------------------------------------------------
extern "C" void kernel_launch(void* const* d_in, const int* in_sizes, int n_in,
                              void* d_out, int out_size, void* d_ws, size_t ws_size,
                              hipStream_t stream) {
    const float* x = (const float*)d_in[0];
    // l0 fwd: 1..4, l0 rev: 5..8, l1 fwd: 9..12, l1 rev: 13..16, fc: 17,18
    char* ws = (char*)d_ws;
    const size_t out0_b = (size_t)NB * TT * 128 * 4;  // 134.2 MB (u32 hi|lo)

    unsigned int* out0 = (unsigned int*)ws;
    float* h1f = (float*)(ws + out0_b);

    lstm_l0<<<256, 256, 0, stream>>>(
        x, (const float*)d_in[1], (const float*)d_in[2], (const float*)d_in[3], (const float*)d_in[4],
        (const float*)d_in[5], (const float*)d_in[6], (const float*)d_in[7], (const float*)d_in[8], out0);
    lstm_l1_fused<<<256, 256, 0, stream>>>(
        out0, (const float*)d_in[9], (const float*)d_in[10], (const float*)d_in[11],
        (const float*)d_in[12], h1f);
    lstm_tail<<<1024, 256, 0, stream>>>(
        out0, h1f, (const float*)d_in[13], (const float*)d_in[15], (const float*)d_in[16],
        (const float*)d_in[17], (const float*)d_in[18], (float*)d_out);
}

// Round 9
// 574.002 us; speedup vs baseline: 2.4151x; 1.3256x over previous
//
#include <hip/hip_runtime.h>
#include <hip/hip_bf16.h>

#define HH 64      // hidden
#define TT 256     // seq len
#define NB 1024    // batch
#define GG 256     // 4*H gates
#define DD0 5      // layer-0 input dim
#define DD1 128    // layer-1 input dim (2*H)

typedef __attribute__((ext_vector_type(8))) short bf16x8;  // 8 bf16 = 4 VGPR
typedef __attribute__((ext_vector_type(4))) float f32x4;   // MFMA C/D frag

#define MFMA16(a, b, c) __builtin_amdgcn_mfma_f32_16x16x32_bf16((a), (b), (c), 0, 0, 0)

// v_rcp_f32: 1 trans op vs ~11-instr IEEE divide (round-8 win, keep).
__device__ __forceinline__ float rcp_fast(float x) {
    float r;
    asm("v_rcp_f32 %0, %1" : "=v"(r) : "v"(x));
    return r;
}
__device__ __forceinline__ float sigf(float x) { return rcp_fast(1.0f + __expf(-x)); }
__device__ __forceinline__ float tanh_fast(float x) { return 2.0f * rcp_fast(1.0f + __expf(-2.0f * x)) - 1.0f; }

__device__ __forceinline__ float bf2f(short s) {
    unsigned int u = ((unsigned int)(unsigned short)s) << 16;
    return __builtin_bit_cast(float, u);
}
__device__ __forceinline__ short f2bf_rne(float x) {
    unsigned int u = __builtin_bit_cast(unsigned int, x);
    u += 0x7fffu + ((u >> 16) & 1u);  // round-to-nearest-even
    return (short)(u >> 16);
}

// Lane-linear A-fragment store for h (conflict-free ds_read_b128):
// reader lane l, seg s reads shorts [s*512 + l*8, +8) == h[row=l&15][k=s*32+8*(l>>4)+e].
__device__ __forceinline__ int hsf_waddr(int u, int row) {
    return ((u >> 5) * 512) + (((u >> 3) & 3) * 128) + row * 8 + (u & 7);  // lo plane: +1024
}

// out0 layout (PLANAR, round-8 lesson: interleaved u32 cost ~130 unpack-VALU
// per step per wave in l1): plane0 = h_hi bf16 [b][t][128], plane1 = h_lo at
// +NB*TT*128 shorts. unit 0..63 = fwd, 64..127 = bwd.
#define PLANE ((size_t)NB * TT * 128)

// ---------------------------------------------------------------------------
// Layer 0 (r8-proven): 256 blocks = 128 row-octets x 2 dirs, 1 block/CU.
// Wave w owns n-tile quad {w,w+4,w+8,w+12}; lanes rg<2 update rows rg*4+r.
// ---------------------------------------------------------------------------
__launch_bounds__(256, 1)
__global__ void lstm_l0(const float* __restrict__ x,
                        const float* __restrict__ w_ih_f, const float* __restrict__ w_hh_f,
                        const float* __restrict__ b_ih_f, const float* __restrict__ b_hh_f,
                        const float* __restrict__ w_ih_r, const float* __restrict__ w_hh_r,
                        const float* __restrict__ b_ih_r, const float* __restrict__ b_hh_r,
                        short* __restrict__ out0) {
    const int tid  = threadIdx.x;
    const int w    = tid >> 6;
    const int l    = tid & 63;
    const int col  = l & 15;
    const int rg   = l >> 4;
    const int dir  = blockIdx.x & 1;
    const int row0 = (blockIdx.x >> 1) * 8;
    const int u    = w * 16 + col;

    const float* w_ih = dir ? w_ih_r : w_ih_f;
    const float* w_hh = dir ? w_hh_r : w_hh_f;
    const float* b_ih = dir ? b_ih_r : b_ih_f;
    const float* b_hh = dir ? b_hh_r : b_hh_f;

    __shared__ __align__(16) float xs[8 * TT * DD0];  // 40 KB
    __shared__ __align__(16) short hsf[2][2048];      // 8 KB

    {   // stage x: 8 rows x 1280 contiguous floats
        const float4* src = (const float4*)(x + (size_t)row0 * TT * DD0);
        for (int i = tid; i < 8 * TT * DD0 / 4; i += 256) ((float4*)xs)[i] = src[i];
    }
    for (int i = tid; i < 2 * 2048; i += 256) ((short*)hsf)[i] = 0;

    bf16x8 whh_hi[4][2], whh_lo[4][2];
#pragma unroll
    for (int q = 0; q < 4; ++q) {
        const int gate = (w + 4 * q) * 16 + col;
#pragma unroll
        for (int ks = 0; ks < 2; ++ks) {
            const float* src = w_hh + gate * HH + ks * 32 + 8 * rg;
#pragma unroll
            for (int e = 0; e < 8; ++e) {
                float v = src[e];
                short h16 = f2bf_rne(v);
                whh_hi[q][ks][e] = h16;
                whh_lo[q][ks][e] = f2bf_rne(v - bf2f(h16));
            }
        }
    }
    float wxi[4][DD0], bb[4];
#pragma unroll
    for (int gi = 0; gi < 4; ++gi) {
        const int gate = u + 64 * gi;
#pragma unroll
        for (int d = 0; d < DD0; ++d) wxi[gi][d] = w_ih[gate * DD0 + d];
        bb[gi] = b_ih[gate] + b_hh[gate];
    }

    f32x4 cc = {0.f, 0.f, 0.f, 0.f};
    __syncthreads();

    for (int t = 0; t < TT; ++t) {
        const int tt  = dir ? (TT - 1 - t) : t;
        const int cur = t & 1, nxt = cur ^ 1;
        const short* hb = &hsf[cur][0];
        bf16x8 ah0 = *(const bf16x8*)&hb[0 * 512 + l * 8];
        bf16x8 ah1 = *(const bf16x8*)&hb[1 * 512 + l * 8];
        bf16x8 ah2 = *(const bf16x8*)&hb[2 * 512 + l * 8];
        bf16x8 ah3 = *(const bf16x8*)&hb[3 * 512 + l * 8];
        f32x4 acc[4];
#pragma unroll
        for (int q = 0; q < 4; ++q) {
            f32x4 a = {0.f, 0.f, 0.f, 0.f};
            a = MFMA16(ah0, whh_hi[q][0], a);
            a = MFMA16(ah1, whh_hi[q][1], a);
            a = MFMA16(ah2, whh_hi[q][0], a);   // h_lo * w_hi
            a = MFMA16(ah3, whh_hi[q][1], a);
            a = MFMA16(ah0, whh_lo[q][0], a);   // h_hi * w_lo
            a = MFMA16(ah1, whh_lo[q][1], a);
            acc[q] = a;
        }
        if (rg < 2) {
#pragma unroll
            for (int r = 0; r < 4; ++r) {
                const int row = rg * 4 + r;
                const float* xr = &xs[row * TT * DD0 + tt * DD0];
                const float xv0 = xr[0], xv1 = xr[1], xv2 = xr[2], xv3 = xr[3], xv4 = xr[4];
                float g4[4];
#pragma unroll
                for (int gi = 0; gi < 4; ++gi)
                    g4[gi] = acc[gi][r] + bb[gi]
                           + wxi[gi][0] * xv0 + wxi[gi][1] * xv1 + wxi[gi][2] * xv2
                           + wxi[gi][3] * xv3 + wxi[gi][4] * xv4;
                const float cn = sigf(g4[1]) * cc[r] + sigf(g4[0]) * tanh_fast(g4[2]);
                const float hn = sigf(g4[3]) * tanh_fast(cn);
                cc[r] = cn;
                const short hi16 = f2bf_rne(hn);
                const short lo16 = f2bf_rne(hn - bf2f(hi16));
                const int wa = hsf_waddr(u, row);
                hsf[nxt][wa]        = hi16;
                hsf[nxt][wa + 1024] = lo16;
                const size_t ob = ((size_t)(row0 + row) * TT + tt) * 128 + dir * 64 + u;
                out0[ob]         = hi16;
                out0[ob + PLANE] = lo16;
            }
        }
        __syncthreads();
    }
}

// ---------------------------------------------------------------------------
// Layer 1 forward, PRODUCER-CONSUMER: 256 blocks x 512 threads (8 waves,
// 2 waves/SIMD). Waves 0-3 (loaders, quad m): ihacc(t+1) = x(t+1) @ W_ih^T
// via 48 MFMA/step, W_ih frags in REGISTERS (no 128 KB LDS), into an 8 KB
// LDS double buffer. Waves 4-7 (compute, quad w): 24 hh-MFMA + gate update.
// The ih GEMM leaves the serial chain entirely (it depends on x only).
// One barrier/step; LDS 16 KB total.
// ---------------------------------------------------------------------------
__launch_bounds__(512, 2)
__global__ void lstm_l1_pc(const short* __restrict__ h0,
                           const float* __restrict__ w_ih, const float* __restrict__ w_hh,
                           const float* __restrict__ b_ih, const float* __restrict__ b_hh,
                           float* __restrict__ h_last) {
    const int tid  = threadIdx.x;
    const int W    = tid >> 6;   // wave 0..7
    const int l    = tid & 63;
    const int col  = l & 15;
    const int rg   = l >> 4;
    const int row0 = blockIdx.x * 4;

    __shared__ __align__(16) short hsf[2][2048];      // 8 KB h hi/lo frags
    __shared__ __align__(16) float ihacc[2][4][GG];   // 8 KB [buf][row][gate]

    for (int i = tid; i < 2 * 2048; i += 512) ((short*)hsf)[i] = 0;

    if (W < 4) {
        // ======================= LOADER =======================
        const int m = W;
        bf16x8 wf_hi[4][4], wf_lo[4][4];   // 32 frags = 128 VGPR
#pragma unroll
        for (int q = 0; q < 4; ++q) {
            const int gate = (m + 4 * q) * 16 + col;
#pragma unroll
            for (int ks = 0; ks < 4; ++ks) {
                const float* src = w_ih + gate * DD1 + ks * 32 + 8 * rg;
#pragma unroll
                for (int e = 0; e < 8; ++e) {
                    float v = src[e];
                    short h16 = f2bf_rne(v);
                    wf_hi[q][ks][e] = h16;
                    wf_lo[q][ks][e] = f2bf_rne(v - bf2f(h16));
                }
            }
        }
        const int arow = row0 + (col < 4 ? col : 3);  // A rows 4..15 clamped (C rows unread)
        const short* xh = h0 + (size_t)arow * TT * 128 + 8 * rg;
        const short* xl = xh + PLANE;

        bf16x8 xA[8], xB[8];
        auto loadx = [&](int t, bf16x8 (&xr)[8]) {
            const size_t base = (size_t)t * 128;
#pragma unroll
            for (int ks = 0; ks < 4; ++ks) {
                xr[ks]     = *(const bf16x8*)&xh[base + ks * 32];
                xr[4 + ks] = *(const bf16x8*)&xl[base + ks * 32];
            }
        };
        auto ih_step = [&](const bf16x8 (&xr)[8], int buf) {
            f32x4 acc[4];
#pragma unroll
            for (int q = 0; q < 4; ++q) {
                f32x4 a = {0.f, 0.f, 0.f, 0.f};
#pragma unroll
                for (int ks = 0; ks < 4; ++ks) {
                    a = MFMA16(xr[ks],     wf_hi[q][ks], a);   // x_hi * w_hi
                    a = MFMA16(xr[4 + ks], wf_hi[q][ks], a);   // x_lo * w_hi
                    a = MFMA16(xr[ks],     wf_lo[q][ks], a);   // x_hi * w_lo
                }
                acc[q] = a;
            }
            if (rg == 0) {
#pragma unroll
                for (int q = 0; q < 4; ++q) {
                    const int gate = (m + 4 * q) * 16 + col;
#pragma unroll
                    for (int r = 0; r < 4; ++r) ihacc[buf][r][gate] = acc[q][r];
                }
            }
        };

        loadx(0, xA);
        ih_step(xA, 0);       // ihacc[0] for t=0
        loadx(1, xB);
        __syncthreads();      // prologue barrier

        for (int t = 0; t < TT; t += 2) {
            // iter t (even): produce ihacc[1] for t+1 from xB = x(t+1)
            if (t + 1 < TT) ih_step(xB, 1);
            if (t + 2 < TT) loadx(t + 2, xA);
            __syncthreads();
            // iter t+1 (odd): produce ihacc[0] for t+2 from xA = x(t+2)
            if (t + 2 < TT) ih_step(xA, 0);
            if (t + 3 < TT) loadx(t + 3, xB);
            __syncthreads();
        }
    } else {
        // ======================= COMPUTE =======================
        const int w = W - 4;
        const int u = w * 16 + col;

        bf16x8 whh_hi[4][2], whh_lo[4][2];
#pragma unroll
        for (int q = 0; q < 4; ++q) {
            const int gate = (w + 4 * q) * 16 + col;
#pragma unroll
            for (int ks = 0; ks < 2; ++ks) {
                const float* src = w_hh + gate * HH + ks * 32 + 8 * rg;
#pragma unroll
                for (int e = 0; e < 8; ++e) {
                    float v = src[e];
                    short h16 = f2bf_rne(v);
                    whh_hi[q][ks][e] = h16;
                    whh_lo[q][ks][e] = f2bf_rne(v - bf2f(h16));
                }
            }
        }
        float bb[4];
#pragma unroll
        for (int gi = 0; gi < 4; ++gi) bb[gi] = b_ih[u + 64 * gi] + b_hh[u + 64 * gi];

        f32x4 cc = {0.f, 0.f, 0.f, 0.f};
        __syncthreads();      // prologue barrier

        auto step = [&](int t, int cur) {
            const int nxt = cur ^ 1;
            // ih pre-activations (early LDS reads, hide under MFMA)
            float ihv[4][4];
            if (rg == 0) {
#pragma unroll
                for (int q = 0; q < 4; ++q)
#pragma unroll
                    for (int r = 0; r < 4; ++r) ihv[q][r] = ihacc[cur][r][u + 64 * q];
            }
            const short* hb = &hsf[cur][0];
            bf16x8 ah0 = *(const bf16x8*)&hb[0 * 512 + l * 8];
            bf16x8 ah1 = *(const bf16x8*)&hb[1 * 512 + l * 8];
            bf16x8 ah2 = *(const bf16x8*)&hb[2 * 512 + l * 8];
            bf16x8 ah3 = *(const bf16x8*)&hb[3 * 512 + l * 8];
            f32x4 acc[4];
#pragma unroll
            for (int q = 0; q < 4; ++q) {
                f32x4 a = {0.f, 0.f, 0.f, 0.f};
                a = MFMA16(ah0, whh_hi[q][0], a);
                a = MFMA16(ah1, whh_hi[q][1], a);
                a = MFMA16(ah2, whh_hi[q][0], a);
                a = MFMA16(ah3, whh_hi[q][1], a);
                a = MFMA16(ah0, whh_lo[q][0], a);
                a = MFMA16(ah1, whh_lo[q][1], a);
                acc[q] = a;
            }
            if (rg == 0) {
#pragma unroll
                for (int r = 0; r < 4; ++r) {
                    const float gi_ = acc[0][r] + ihv[0][r] + bb[0];
                    const float gf_ = acc[1][r] + ihv[1][r] + bb[1];
                    const float gg_ = acc[2][r] + ihv[2][r] + bb[2];
                    const float go_ = acc[3][r] + ihv[3][r] + bb[3];
                    const float cn = sigf(gf_) * cc[r] + sigf(gi_) * tanh_fast(gg_);
                    const float hn = sigf(go_) * tanh_fast(cn);
                    cc[r] = cn;
                    const short hi16 = f2bf_rne(hn);
                    const int wa = hsf_waddr(u, r);
                    hsf[nxt][wa]        = hi16;
                    hsf[nxt][wa + 1024] = f2bf_rne(hn - bf2f(hi16));
                    if (t == TT - 1) h_last[(size_t)(row0 + r) * HH + u] = hn;
                }
            }
            __syncthreads();
        };

        for (int t = 0; t < TT; t += 2) {
            step(t, 0);
            step(t + 1, 1);
        }
    }
}

// ---------------------------------------------------------------------------
// Tail: layer-1 backward is ONE step at t=T-1 from zero state (h0=0 kills the
// w_hh term), then FC. 1024 blocks, 256 threads. Planar in0.
// ---------------------------------------------------------------------------
__global__ void lstm_tail(const short* __restrict__ in0,
                          const float* __restrict__ h1f,
                          const float* __restrict__ w_ih_r,
                          const float* __restrict__ b_ih_r, const float* __restrict__ b_hh_r,
                          const float* __restrict__ fc_w, const float* __restrict__ fc_b,
                          float* __restrict__ out) {
    const int b   = blockIdx.x;
    const int tid = threadIdx.x;
    __shared__ __align__(16) float insl[DD1];
    __shared__ __align__(16) float hb[HH];
    __shared__ __align__(16) float gsh[256];

    if (tid < DD1) {
        const size_t base = ((size_t)b * TT + (TT - 1)) * 128 + tid;
        insl[tid] = bf2f(in0[base]) + bf2f(in0[base + PLANE]);
    }
    __syncthreads();

    float a0 = b_ih_r[tid] + b_hh_r[tid], a1 = 0.f, a2 = 0.f, a3 = 0.f;
    const float4* in4 = (const float4*)insl;
#pragma unroll
    for (int kk = 0; kk < 32; ++kk) {
        float4 iv = in4[kk];
        float4 wv = *(const float4*)&w_ih_r[tid * DD1 + 4 * kk];
        a0 += wv.x * iv.x;
        a1 += wv.y * iv.y;
        a2 += wv.z * iv.z;
        a3 += wv.w * iv.w;
    }
    gsh[tid] = (a0 + a1) + (a2 + a3);
    __syncthreads();

    if (tid < HH) {
        const float gi = gsh[tid], gc = gsh[tid + 128], go = gsh[tid + 192];
        const float ccv = sigf(gi) * tanh_fast(gc);  // c_prev = 0
        hb[tid] = sigf(go) * tanh_fast(ccv);
    }
    __syncthreads();

    if (tid < 64) {
        float p = fc_w[tid] * h1f[(size_t)b * HH + tid] + fc_w[HH + tid] * hb[tid];
#pragma unroll
        for (int off = 32; off; off >>= 1) p += __shfl_xor(p, off);
        if (tid == 0) out[b] = p + fc_b[0];
    }
}

// ---------------------------------------------------------------------------
extern "C" void kernel_launch(void* const* d_in, const int* in_sizes, int n_in,
                              void* d_out, int out_size, void* d_ws, size_t ws_size,
                              hipStream_t stream) {
    const float* x = (const float*)d_in[0];
    // l0 fwd: 1..4, l0 rev: 5..8, l1 fwd: 9..12, l1 rev: 13..16, fc: 17,18
    char* ws = (char*)d_ws;
    const size_t out0_b = 2 * PLANE * sizeof(short);  // 134.2 MB (hi plane + lo plane)

    short* out0 = (short*)ws;
    float* h1f  = (float*)(ws + out0_b);

    lstm_l0<<<256, 256, 0, stream>>>(
        x, (const float*)d_in[1], (const float*)d_in[2], (const float*)d_in[3], (const float*)d_in[4],
        (const float*)d_in[5], (const float*)d_in[6], (const float*)d_in[7], (const float*)d_in[8], out0);
    lstm_l1_pc<<<256, 512, 0, stream>>>(
        out0, (const float*)d_in[9], (const float*)d_in[10], (const float*)d_in[11],
        (const float*)d_in[12], h1f);
    lstm_tail<<<1024, 256, 0, stream>>>(
        out0, h1f, (const float*)d_in[13], (const float*)d_in[15], (const float*)d_in[16],
        (const float*)d_in[17], (const float*)d_in[18], (float*)d_out);
}

// Round 10
// 517.525 us; speedup vs baseline: 2.6786x; 1.1091x over previous
//
#include <hip/hip_runtime.h>
#include <hip/hip_bf16.h>

#define HH 64      // hidden
#define TT 256     // seq len
#define NB 1024    // batch
#define GG 256     // 4*H gates
#define DD0 5      // layer-0 input dim
#define DD1 128    // layer-1 input dim (2*H)

typedef __attribute__((ext_vector_type(8))) short bf16x8;  // 8 bf16 = 4 VGPR
typedef __attribute__((ext_vector_type(4))) float f32x4;   // MFMA C/D frag

#define MFMA16(a, b, c) __builtin_amdgcn_mfma_f32_16x16x32_bf16((a), (b), (c), 0, 0, 0)

// v_rcp_f32: 1 trans op vs ~11-instr IEEE divide (round-8 win, keep).
__device__ __forceinline__ float rcp_fast(float x) {
    float r;
    asm("v_rcp_f32 %0, %1" : "=v"(r) : "v"(x));
    return r;
}
__device__ __forceinline__ float sigf(float x) { return rcp_fast(1.0f + __expf(-x)); }
__device__ __forceinline__ float tanh_fast(float x) { return 2.0f * rcp_fast(1.0f + __expf(-2.0f * x)) - 1.0f; }

__device__ __forceinline__ float bf2f(short s) {
    unsigned int u = ((unsigned int)(unsigned short)s) << 16;
    return __builtin_bit_cast(float, u);
}
__device__ __forceinline__ short f2bf_rne(float x) {
    unsigned int u = __builtin_bit_cast(unsigned int, x);
    u += 0x7fffu + ((u >> 16) & 1u);  // round-to-nearest-even
    return (short)(u >> 16);
}

// Lane-linear A-fragment store for h (conflict-free ds_read_b128):
// reader lane l, seg s reads shorts [s*512 + l*8, +8) == h[row=l&15][k=s*32+8*(l>>4)+e].
__device__ __forceinline__ int hsf_waddr(int u, int row) {
    return ((u >> 5) * 512) + (((u >> 3) & 3) * 128) + row * 8 + (u & 7);  // lo plane: +1024
}

// out0: PLANAR. plane0 = h_hi bf16 [b][t][128], plane1 = h_lo at +PLANE shorts.
#define PLANE ((size_t)NB * TT * 128)

// ---------------------------------------------------------------------------
// Layer 0 (r8-proven, unchanged): 256 blocks = 128 row-octets x 2 dirs.
// ---------------------------------------------------------------------------
__launch_bounds__(256, 1)
__global__ void lstm_l0(const float* __restrict__ x,
                        const float* __restrict__ w_ih_f, const float* __restrict__ w_hh_f,
                        const float* __restrict__ b_ih_f, const float* __restrict__ b_hh_f,
                        const float* __restrict__ w_ih_r, const float* __restrict__ w_hh_r,
                        const float* __restrict__ b_ih_r, const float* __restrict__ b_hh_r,
                        short* __restrict__ out0) {
    const int tid  = threadIdx.x;
    const int w    = tid >> 6;
    const int l    = tid & 63;
    const int col  = l & 15;
    const int rg   = l >> 4;
    const int dir  = blockIdx.x & 1;
    const int row0 = (blockIdx.x >> 1) * 8;
    const int u    = w * 16 + col;

    const float* w_ih = dir ? w_ih_r : w_ih_f;
    const float* w_hh = dir ? w_hh_r : w_hh_f;
    const float* b_ih = dir ? b_ih_r : b_ih_f;
    const float* b_hh = dir ? b_hh_r : b_hh_f;

    __shared__ __align__(16) float xs[8 * TT * DD0];  // 40 KB
    __shared__ __align__(16) short hsf[2][2048];      // 8 KB

    {
        const float4* src = (const float4*)(x + (size_t)row0 * TT * DD0);
        for (int i = tid; i < 8 * TT * DD0 / 4; i += 256) ((float4*)xs)[i] = src[i];
    }
    for (int i = tid; i < 2 * 2048; i += 256) ((short*)hsf)[i] = 0;

    bf16x8 whh_hi[4][2], whh_lo[4][2];
#pragma unroll
    for (int q = 0; q < 4; ++q) {
        const int gate = (w + 4 * q) * 16 + col;
#pragma unroll
        for (int ks = 0; ks < 2; ++ks) {
            const float* src = w_hh + gate * HH + ks * 32 + 8 * rg;
#pragma unroll
            for (int e = 0; e < 8; ++e) {
                float v = src[e];
                short h16 = f2bf_rne(v);
                whh_hi[q][ks][e] = h16;
                whh_lo[q][ks][e] = f2bf_rne(v - bf2f(h16));
            }
        }
    }
    float wxi[4][DD0], bb[4];
#pragma unroll
    for (int gi = 0; gi < 4; ++gi) {
        const int gate = u + 64 * gi;
#pragma unroll
        for (int d = 0; d < DD0; ++d) wxi[gi][d] = w_ih[gate * DD0 + d];
        bb[gi] = b_ih[gate] + b_hh[gate];
    }

    f32x4 cc = {0.f, 0.f, 0.f, 0.f};
    __syncthreads();

    for (int t = 0; t < TT; ++t) {
        const int tt  = dir ? (TT - 1 - t) : t;
        const int cur = t & 1, nxt = cur ^ 1;
        const short* hb = &hsf[cur][0];
        bf16x8 ah0 = *(const bf16x8*)&hb[0 * 512 + l * 8];
        bf16x8 ah1 = *(const bf16x8*)&hb[1 * 512 + l * 8];
        bf16x8 ah2 = *(const bf16x8*)&hb[2 * 512 + l * 8];
        bf16x8 ah3 = *(const bf16x8*)&hb[3 * 512 + l * 8];
        f32x4 acc[4];
#pragma unroll
        for (int q = 0; q < 4; ++q) {
            f32x4 a = {0.f, 0.f, 0.f, 0.f};
            a = MFMA16(ah0, whh_hi[q][0], a);
            a = MFMA16(ah1, whh_hi[q][1], a);
            a = MFMA16(ah2, whh_hi[q][0], a);
            a = MFMA16(ah3, whh_hi[q][1], a);
            a = MFMA16(ah0, whh_lo[q][0], a);
            a = MFMA16(ah1, whh_lo[q][1], a);
            acc[q] = a;
        }
        if (rg < 2) {
#pragma unroll
            for (int r = 0; r < 4; ++r) {
                const int row = rg * 4 + r;
                const float* xr = &xs[row * TT * DD0 + tt * DD0];
                const float xv0 = xr[0], xv1 = xr[1], xv2 = xr[2], xv3 = xr[3], xv4 = xr[4];
                float g4[4];
#pragma unroll
                for (int gi = 0; gi < 4; ++gi)
                    g4[gi] = acc[gi][r] + bb[gi]
                           + wxi[gi][0] * xv0 + wxi[gi][1] * xv1 + wxi[gi][2] * xv2
                           + wxi[gi][3] * xv3 + wxi[gi][4] * xv4;
                const float cn = sigf(g4[1]) * cc[r] + sigf(g4[0]) * tanh_fast(g4[2]);
                const float hn = sigf(g4[3]) * tanh_fast(cn);
                cc[r] = cn;
                const short hi16 = f2bf_rne(hn);
                const short lo16 = f2bf_rne(hn - bf2f(hi16));
                const int wa = hsf_waddr(u, row);
                hsf[nxt][wa]        = hi16;
                hsf[nxt][wa + 1024] = lo16;
                const size_t ob = ((size_t)(row0 + row) * TT + tt) * 128 + dir * 64 + u;
                out0[ob]         = hi16;
                out0[ob + PLANE] = lo16;
            }
        }
        __syncthreads();
    }
}

// ---------------------------------------------------------------------------
// Layer 1, PRODUCER-CONSUMER with 4-STEP-BATCHED loaders. 256 blocks x 512
// threads. Loader A-row a encodes (j = a>>2, rr = a&3): one 16x16 MFMA tile
// covers 4 rows x 4 timesteps -> 100% M utilization, 12 MFMA per step-slot
// (vs 48 in round 9). C row = rg*4+reg -> j=rg, rr=reg (all lanes write).
// Compute waves (4-7) unchanged: 24 hh-MFMA + gate update per step.
// ---------------------------------------------------------------------------
__launch_bounds__(512, 2)
__global__ void lstm_l1_pc(const short* __restrict__ h0,
                           const float* __restrict__ w_ih, const float* __restrict__ w_hh,
                           const float* __restrict__ b_ih, const float* __restrict__ b_hh,
                           float* __restrict__ h_last) {
    const int tid  = threadIdx.x;
    const int W    = tid >> 6;   // wave 0..7
    const int l    = tid & 63;
    const int col  = l & 15;
    const int rg   = l >> 4;
    const int row0 = blockIdx.x * 4;

    __shared__ __align__(16) short hsf[2][2048];          // 8 KB h hi/lo frags
    __shared__ __align__(16) float ihacc[2][4][4][GG];    // 32 KB [buf][j][r][gate]

    for (int i = tid; i < 2 * 2048; i += 512) ((short*)hsf)[i] = 0;

    if (W < 4) {
        // ======================= LOADER =======================
        const int m = W;
        bf16x8 wf_hi[4][4], wf_lo[4][4];   // 32 frags = 128 VGPR
#pragma unroll
        for (int q = 0; q < 4; ++q) {
            const int gate = (m + 4 * q) * 16 + col;
#pragma unroll
            for (int ks = 0; ks < 4; ++ks) {
                const float* src = w_ih + gate * DD1 + ks * 32 + 8 * rg;
#pragma unroll
                for (int e = 0; e < 8; ++e) {
                    float v = src[e];
                    short h16 = f2bf_rne(v);
                    wf_hi[q][ks][e] = h16;
                    wf_lo[q][ks][e] = f2bf_rne(v - bf2f(h16));
                }
            }
        }
        // this lane's A-row: (j = col>>2, rr = col&3)
        const int arr = col & 3, aj = col >> 2;
        const short* xh = h0 + ((size_t)(row0 + arr) * TT + aj) * 128 + 8 * rg;
        const short* xl = xh + PLANE;

        bf16x8 xA[8], xB[8];
        auto loadx = [&](int tbase, bf16x8 (&xr)[8]) {
            const size_t base = (size_t)tbase * 128;
#pragma unroll
            for (int ks = 0; ks < 4; ++ks) {
                xr[ks]     = *(const bf16x8*)&xh[base + ks * 32];
                xr[4 + ks] = *(const bf16x8*)&xl[base + ks * 32];
            }
        };
        auto ih_q = [&](int q, const bf16x8 (&xr)[8], int buf) {
            f32x4 a = {0.f, 0.f, 0.f, 0.f};
#pragma unroll
            for (int ks = 0; ks < 4; ++ks) {
                a = MFMA16(xr[ks],     wf_hi[q][ks], a);   // x_hi * w_hi
                a = MFMA16(xr[4 + ks], wf_hi[q][ks], a);   // x_lo * w_hi
                a = MFMA16(xr[ks],     wf_lo[q][ks], a);   // x_hi * w_lo
            }
            const int gate = (m + 4 * q) * 16 + col;
#pragma unroll
            for (int r = 0; r < 4; ++r) ihacc[buf][rg][r][gate] = a[r];
        };

        // prologue: ih(batch 0) -> ihacc[0]; xB <- x(batch 1)
        loadx(0, xA);
        ih_q(0, xA, 0); ih_q(1, xA, 0); ih_q(2, xA, 0); ih_q(3, xA, 0);
        loadx(4, xB);
        __syncthreads();

        for (int tb = 0; tb < TT; tb += 8) {
            // batch B0 (even): consume xB = x(B0+1) -> ihacc[1]; xA <- x(B0+2)
            if (tb + 8 < TT) loadx(tb + 8, xA);
            ih_q(0, xB, 1); __syncthreads();
            ih_q(1, xB, 1); __syncthreads();
            ih_q(2, xB, 1); __syncthreads();
            ih_q(3, xB, 1); __syncthreads();
            // batch B1 (odd): consume xA = x(B1+1) -> ihacc[0]; xB <- x(B1+2)
            if (tb + 12 < TT) loadx(tb + 12, xB);
            const bool doih = (tb + 8 < TT);
            if (doih) ih_q(0, xA, 0);
            __syncthreads();
            if (doih) ih_q(1, xA, 0);
            __syncthreads();
            if (doih) ih_q(2, xA, 0);
            __syncthreads();
            if (doih) ih_q(3, xA, 0);
            __syncthreads();
        }
    } else {
        // ======================= COMPUTE =======================
        const int w = W - 4;
        const int u = w * 16 + col;

        bf16x8 whh_hi[4][2], whh_lo[4][2];
#pragma unroll
        for (int q = 0; q < 4; ++q) {
            const int gate = (w + 4 * q) * 16 + col;
#pragma unroll
            for (int ks = 0; ks < 2; ++ks) {
                const float* src = w_hh + gate * HH + ks * 32 + 8 * rg;
#pragma unroll
                for (int e = 0; e < 8; ++e) {
                    float v = src[e];
                    short h16 = f2bf_rne(v);
                    whh_hi[q][ks][e] = h16;
                    whh_lo[q][ks][e] = f2bf_rne(v - bf2f(h16));
                }
            }
        }
        float bb[4];
#pragma unroll
        for (int gi = 0; gi < 4; ++gi) bb[gi] = b_ih[u + 64 * gi] + b_hh[u + 64 * gi];

        f32x4 cc = {0.f, 0.f, 0.f, 0.f};
        __syncthreads();      // prologue barrier

        auto step = [&](int t, int k) {   // k = t & 7 (compile-time via unroll)
            const int cur = k & 1, nxt = cur ^ 1;
            const int j = k & 3, ib = k >> 2;
            // ih pre-activations (early LDS reads, hide under MFMA)
            float ihv[4][4];
            if (rg == 0) {
#pragma unroll
                for (int q = 0; q < 4; ++q)
#pragma unroll
                    for (int r = 0; r < 4; ++r) ihv[q][r] = ihacc[ib][j][r][u + 64 * q];
            }
            const short* hb = &hsf[cur][0];
            bf16x8 ah0 = *(const bf16x8*)&hb[0 * 512 + l * 8];
            bf16x8 ah1 = *(const bf16x8*)&hb[1 * 512 + l * 8];
            bf16x8 ah2 = *(const bf16x8*)&hb[2 * 512 + l * 8];
            bf16x8 ah3 = *(const bf16x8*)&hb[3 * 512 + l * 8];
            f32x4 acc[4];
#pragma unroll
            for (int q = 0; q < 4; ++q) {
                f32x4 a = {0.f, 0.f, 0.f, 0.f};
                a = MFMA16(ah0, whh_hi[q][0], a);
                a = MFMA16(ah1, whh_hi[q][1], a);
                a = MFMA16(ah2, whh_hi[q][0], a);
                a = MFMA16(ah3, whh_hi[q][1], a);
                a = MFMA16(ah0, whh_lo[q][0], a);
                a = MFMA16(ah1, whh_lo[q][1], a);
                acc[q] = a;
            }
            if (rg == 0) {
#pragma unroll
                for (int r = 0; r < 4; ++r) {
                    const float gi_ = acc[0][r] + ihv[0][r] + bb[0];
                    const float gf_ = acc[1][r] + ihv[1][r] + bb[1];
                    const float gg_ = acc[2][r] + ihv[2][r] + bb[2];
                    const float go_ = acc[3][r] + ihv[3][r] + bb[3];
                    const float cn = sigf(gf_) * cc[r] + sigf(gi_) * tanh_fast(gg_);
                    const float hn = sigf(go_) * tanh_fast(cn);
                    cc[r] = cn;
                    const short hi16 = f2bf_rne(hn);
                    const int wa = hsf_waddr(u, r);
                    hsf[nxt][wa]        = hi16;
                    hsf[nxt][wa + 1024] = f2bf_rne(hn - bf2f(hi16));
                    if (t == TT - 1) h_last[(size_t)(row0 + r) * HH + u] = hn;
                }
            }
            __syncthreads();
        };

        for (int tb = 0; tb < TT; tb += 8) {
#pragma unroll
            for (int k = 0; k < 8; ++k) step(tb + k, k);
        }
    }
}

// ---------------------------------------------------------------------------
// Tail: layer-1 backward is ONE step at t=T-1 from zero state, then FC.
// ---------------------------------------------------------------------------
__global__ void lstm_tail(const short* __restrict__ in0,
                          const float* __restrict__ h1f,
                          const float* __restrict__ w_ih_r,
                          const float* __restrict__ b_ih_r, const float* __restrict__ b_hh_r,
                          const float* __restrict__ fc_w, const float* __restrict__ fc_b,
                          float* __restrict__ out) {
    const int b   = blockIdx.x;
    const int tid = threadIdx.x;
    __shared__ __align__(16) float insl[DD1];
    __shared__ __align__(16) float hb[HH];
    __shared__ __align__(16) float gsh[256];

    if (tid < DD1) {
        const size_t base = ((size_t)b * TT + (TT - 1)) * 128 + tid;
        insl[tid] = bf2f(in0[base]) + bf2f(in0[base + PLANE]);
    }
    __syncthreads();

    float a0 = b_ih_r[tid] + b_hh_r[tid], a1 = 0.f, a2 = 0.f, a3 = 0.f;
    const float4* in4 = (const float4*)insl;
#pragma unroll
    for (int kk = 0; kk < 32; ++kk) {
        float4 iv = in4[kk];
        float4 wv = *(const float4*)&w_ih_r[tid * DD1 + 4 * kk];
        a0 += wv.x * iv.x;
        a1 += wv.y * iv.y;
        a2 += wv.z * iv.z;
        a3 += wv.w * iv.w;
    }
    gsh[tid] = (a0 + a1) + (a2 + a3);
    __syncthreads();

    if (tid < HH) {
        const float gi = gsh[tid], gc = gsh[tid + 128], go = gsh[tid + 192];
        const float ccv = sigf(gi) * tanh_fast(gc);  // c_prev = 0
        hb[tid] = sigf(go) * tanh_fast(ccv);
    }
    __syncthreads();

    if (tid < 64) {
        float p = fc_w[tid] * h1f[(size_t)b * HH + tid] + fc_w[HH + tid] * hb[tid];
#pragma unroll
        for (int off = 32; off; off >>= 1) p += __shfl_xor(p, off);
        if (tid == 0) out[b] = p + fc_b[0];
    }
}

// ---------------------------------------------------------------------------
extern "C" void kernel_launch(void* const* d_in, const int* in_sizes, int n_in,
                              void* d_out, int out_size, void* d_ws, size_t ws_size,
                              hipStream_t stream) {
    const float* x = (const float*)d_in[0];
    // l0 fwd: 1..4, l0 rev: 5..8, l1 fwd: 9..12, l1 rev: 13..16, fc: 17,18
    char* ws = (char*)d_ws;
    const size_t out0_b = 2 * PLANE * sizeof(short);  // 134.2 MB (hi + lo planes)

    short* out0 = (short*)ws;
    float* h1f  = (float*)(ws + out0_b);

    lstm_l0<<<256, 256, 0, stream>>>(
        x, (const float*)d_in[1], (const float*)d_in[2], (const float*)d_in[3], (const float*)d_in[4],
        (const float*)d_in[5], (const float*)d_in[6], (const float*)d_in[7], (const float*)d_in[8], out0);
    lstm_l1_pc<<<256, 512, 0, stream>>>(
        out0, (const float*)d_in[9], (const float*)d_in[10], (const float*)d_in[11],
        (const float*)d_in[12], h1f);
    lstm_tail<<<1024, 256, 0, stream>>>(
        out0, h1f, (const float*)d_in[13], (const float*)d_in[15], (const float*)d_in[16],
        (const float*)d_in[17], (const float*)d_in[18], (float*)d_out);
}

// Round 11
// 473.948 us; speedup vs baseline: 2.9249x; 1.0919x over previous
//
#include <hip/hip_runtime.h>
#include <hip/hip_bf16.h>

#define HH 64      // hidden
#define TT 256     // seq len
#define NB 1024    // batch
#define GG 256     // 4*H gates
#define DD0 5      // layer-0 input dim
#define DD1 128    // layer-1 input dim (2*H)

typedef __attribute__((ext_vector_type(8))) short bf16x8;   // 8 bf16 = 4 VGPR
typedef __attribute__((ext_vector_type(4))) float f32x4;    // MFMA C/D frag
typedef __attribute__((ext_vector_type(4))) unsigned int u32x4;

#define MFMA16(a, b, c) __builtin_amdgcn_mfma_f32_16x16x32_bf16((a), (b), (c), 0, 0, 0)

__device__ __forceinline__ float rcp_fast(float x) {
    float r;
    asm("v_rcp_f32 %0, %1" : "=v"(r) : "v"(x));
    return r;
}
__device__ __forceinline__ float sigf(float x) { return rcp_fast(1.0f + __expf(-x)); }
__device__ __forceinline__ float tanh_fast(float x) { return 2.0f * rcp_fast(1.0f + __expf(-2.0f * x)) - 1.0f; }

__device__ __forceinline__ float bf2f(short s) {
    unsigned int u = ((unsigned int)(unsigned short)s) << 16;
    return __builtin_bit_cast(float, u);
}
__device__ __forceinline__ short f2bf_rne(float x) {
    unsigned int u = __builtin_bit_cast(unsigned int, x);
    u += 0x7fffu + ((u >> 16) & 1u);
    return (short)(u >> 16);
}

// Lane-linear A-fragment store for h (conflict-free ds_read_b128):
// reader lane l, seg s reads shorts [s*512 + l*8, +8) == h[row=l&15][k=s*32+8*(l>>4)+e].
__device__ __forceinline__ int hsf_waddr(int u, int row) {
    return ((u >> 5) * 512) + (((u >> 3) & 3) * 128) + row * 8 + (u & 7);  // lo plane: +1024
}

// out0: PACKED u32[b][t][128]: low16 = h_hi bf16, high16 = h_lo bf16.
// unit 0..63 = fwd, 64..127 = bwd. (Unpack lives in l1 LOADER / tail — slack.)

// ---------------------------------------------------------------------------
// Layer 0: 256 blocks = 128 row-octets x 2 dirs. x-part AND bias folded into
// one extra MFMA k-step: A = [xh(5)|xl(5)|xh(5)|1|1], B = [whi|whi|wlo|bbhi|bblo].
// Update g = acc directly (no x-FMA, no bias add). out0 via bumped pointers.
// ---------------------------------------------------------------------------
__launch_bounds__(256, 1)
__global__ void lstm_l0(const float* __restrict__ x,
                        const float* __restrict__ w_ih_f, const float* __restrict__ w_hh_f,
                        const float* __restrict__ b_ih_f, const float* __restrict__ b_hh_f,
                        const float* __restrict__ w_ih_r, const float* __restrict__ w_hh_r,
                        const float* __restrict__ b_ih_r, const float* __restrict__ b_hh_r,
                        unsigned int* __restrict__ out0) {
    const int tid  = threadIdx.x;
    const int w    = tid >> 6;
    const int l    = tid & 63;
    const int col  = l & 15;
    const int rg   = l >> 4;
    const int dir  = blockIdx.x & 1;
    const int row0 = (blockIdx.x >> 1) * 8;
    const int u    = w * 16 + col;

    const float* w_ih = dir ? w_ih_r : w_ih_f;
    const float* w_hh = dir ? w_hh_r : w_hh_f;
    const float* b_ih = dir ? b_ih_r : b_ih_f;
    const float* b_hh = dir ? b_hh_r : b_hh_f;

    // xsp[row][t][0..4]: packed u32 = x_hi | (x_lo<<16); row stride 2056 u32
    // (pad +8 breaks the 8192B power-of-2 row stride -> 2-way instead of 8-way)
    __shared__ __align__(16) unsigned int xsp[8 * 2056];  // 64.3 KB
    __shared__ __align__(16) short hsf[2][2048];          // 8 KB

    for (int i = tid; i < 8 * TT * DD0; i += 256) {
        const int row = i / (TT * DD0);
        const int rem = i - row * (TT * DD0);
        const int t = rem / DD0, d = rem - t * DD0;
        const float v = x[(size_t)row0 * TT * DD0 + i];
        const short hi = f2bf_rne(v);
        const short lo = f2bf_rne(v - bf2f(hi));
        xsp[row * 2056 + t * 8 + d] =
            (unsigned int)(unsigned short)hi | ((unsigned int)(unsigned short)lo << 16);
    }
    for (int i = tid; i < 2 * 2048; i += 256) ((short*)hsf)[i] = 0;

    bf16x8 whh_hi[4][2], whh_lo[4][2];
#pragma unroll
    for (int q = 0; q < 4; ++q) {
        const int gate = (w + 4 * q) * 16 + col;
#pragma unroll
        for (int ks = 0; ks < 2; ++ks) {
            const float* src = w_hh + gate * HH + ks * 32 + 8 * rg;
#pragma unroll
            for (int e = 0; e < 8; ++e) {
                float v = src[e];
                short h16 = f2bf_rne(v);
                whh_hi[q][ks][e] = h16;
                whh_lo[q][ks][e] = f2bf_rne(v - bf2f(h16));
            }
        }
    }
    // x/bias B-fragment (extra k-step), per q
    bf16x8 wxb[4];
#pragma unroll
    for (int q = 0; q < 4; ++q) {
        const int gate = (w + 4 * q) * 16 + col;
        short whi[5], wlo[5];
#pragma unroll
        for (int d = 0; d < DD0; ++d) {
            float v = w_ih[gate * DD0 + d];
            whi[d] = f2bf_rne(v);
            wlo[d] = f2bf_rne(v - bf2f(whi[d]));
        }
        const float bbv = b_ih[gate] + b_hh[gate];
        const short bbh = f2bf_rne(bbv);
        const short bbl = f2bf_rne(bbv - bf2f(bbh));
        bf16x8 bs = {};
        if (rg == 0) {
            bs[0] = whi[0]; bs[1] = whi[1]; bs[2] = whi[2]; bs[3] = whi[3]; bs[4] = whi[4];
            bs[5] = whi[0]; bs[6] = whi[1]; bs[7] = whi[2];
        } else if (rg == 1) {
            bs[0] = whi[3]; bs[1] = whi[4];
            bs[2] = wlo[0]; bs[3] = wlo[1]; bs[4] = wlo[2]; bs[5] = wlo[3]; bs[6] = wlo[4];
            bs[7] = bbh;
        } else if (rg == 2) {
            bs[0] = bbl;
        }
        wxb[q] = bs;
    }

    // constant x A-frag for rg>=2 (slot 16 = 1.0)
    bf16x8 xf = {};
    if (rg == 2) xf[0] = (short)0x3f80;

    // out0 running pointers (4 rows per active lane), bumped +-128 u32/step
    unsigned int* po[4];
    const int t0 = dir ? (TT - 1) : 0;
#pragma unroll
    for (int r = 0; r < 4; ++r) {
        const int row = (rg & 1) * 4 + r;
        po[r] = out0 + ((size_t)(row0 + row) * TT + t0) * 128 + dir * 64 + u;
    }
    const int pstep = dir ? -128 : 128;

    f32x4 cc = {0.f, 0.f, 0.f, 0.f};
    __syncthreads();

    for (int t = 0; t < TT; ++t) {
        const int tt  = dir ? (TT - 1 - t) : t;
        const int cur = t & 1, nxt = cur ^ 1;

        // per-step x A-frag (rg<2 rebuild; rg>=2 constant)
        if (rg < 2) {
            const unsigned int* pp = &xsp[(col & 7) * 2056 + tt * 8];
            const u32x4 p03 = *(const u32x4*)pp;
            const unsigned int p4 = pp[4];
            unsigned int w0, w1, w2, w3;
            if (rg == 0) {
                w0 = (p03[0] & 0xffffu) | (p03[1] << 16);
                w1 = (p03[2] & 0xffffu) | (p03[3] << 16);
                w2 = (p4 & 0xffffu)     | (p03[0] & 0xffff0000u);
                w3 = (p03[1] >> 16)     | (p03[2] & 0xffff0000u);
            } else {
                w0 = (p03[3] >> 16)     | (p4 & 0xffff0000u);
                w1 = (p03[0] & 0xffffu) | (p03[1] << 16);
                w2 = (p03[2] & 0xffffu) | (p03[3] << 16);
                w3 = (p4 & 0xffffu)     | 0x3f800000u;
            }
            u32x4 wv = {w0, w1, w2, w3};
            xf = __builtin_bit_cast(bf16x8, wv);
        }

        const short* hb = &hsf[cur][0];
        bf16x8 ah0 = *(const bf16x8*)&hb[0 * 512 + l * 8];
        bf16x8 ah1 = *(const bf16x8*)&hb[1 * 512 + l * 8];
        bf16x8 ah2 = *(const bf16x8*)&hb[2 * 512 + l * 8];
        bf16x8 ah3 = *(const bf16x8*)&hb[3 * 512 + l * 8];
        f32x4 acc[4];
#pragma unroll
        for (int q = 0; q < 4; ++q) {
            f32x4 a = {0.f, 0.f, 0.f, 0.f};
            a = MFMA16(xf, wxb[q], a);          // x + bias k-step
            a = MFMA16(ah0, whh_hi[q][0], a);
            a = MFMA16(ah1, whh_hi[q][1], a);
            a = MFMA16(ah2, whh_hi[q][0], a);   // h_lo * w_hi
            a = MFMA16(ah3, whh_hi[q][1], a);
            a = MFMA16(ah0, whh_lo[q][0], a);   // h_hi * w_lo
            a = MFMA16(ah1, whh_lo[q][1], a);
            acc[q] = a;
        }
        if (rg < 2) {
#pragma unroll
            for (int r = 0; r < 4; ++r) {
                const int row = rg * 4 + r;
                const float cn = sigf(acc[1][r]) * cc[r] + sigf(acc[0][r]) * tanh_fast(acc[2][r]);
                const float hn = sigf(acc[3][r]) * tanh_fast(cn);
                cc[r] = cn;
                const short hi16 = f2bf_rne(hn);
                const short lo16 = f2bf_rne(hn - bf2f(hi16));
                const int wa = hsf_waddr(u, row);
                hsf[nxt][wa]        = hi16;
                hsf[nxt][wa + 1024] = lo16;
                *po[r] = (unsigned int)(unsigned short)hi16 |
                         ((unsigned int)(unsigned short)lo16 << 16);
                po[r] += pstep;
            }
        }
        __syncthreads();
    }
}

// ---------------------------------------------------------------------------
// Layer 1, PRODUCER-CONSUMER, 4-step-batched loaders (r10 schedule).
// Changes: packed-u32 input (unpack in loader), bias added by loader,
// ihacc layout [buf][j][unit][gi][r] stride-20 -> compute reads 4x b128.
// ---------------------------------------------------------------------------
__global__ __launch_bounds__(512) __attribute__((amdgpu_waves_per_eu(2, 2)))
void lstm_l1_pc(const unsigned int* __restrict__ h0,
                const float* __restrict__ w_ih, const float* __restrict__ w_hh,
                const float* __restrict__ b_ih, const float* __restrict__ b_hh,
                float* __restrict__ h_last) {
    const int tid  = threadIdx.x;
    const int W    = tid >> 6;   // wave 0..7
    const int l    = tid & 63;
    const int col  = l & 15;
    const int rg   = l >> 4;
    const int row0 = blockIdx.x * 4;

    __shared__ __align__(16) short hsf[2][2048];          // 8 KB
    __shared__ __align__(16) float ihaccf[2 * 4 * 64 * 20];  // 40 KB, stride-20/unit

    for (int i = tid; i < 2 * 2048; i += 512) ((short*)hsf)[i] = 0;

    if (W < 4) {
        // ======================= LOADER =======================
        const int m = W;
        bf16x8 wf_hi[4][4], wf_lo[4][4];
        float bbq[4];
#pragma unroll
        for (int q = 0; q < 4; ++q) {
            const int gate = (m + 4 * q) * 16 + col;
            bbq[q] = b_ih[gate] + b_hh[gate];
#pragma unroll
            for (int ks = 0; ks < 4; ++ks) {
                const float* src = w_ih + gate * DD1 + ks * 32 + 8 * rg;
#pragma unroll
                for (int e = 0; e < 8; ++e) {
                    float v = src[e];
                    short h16 = f2bf_rne(v);
                    wf_hi[q][ks][e] = h16;
                    wf_lo[q][ks][e] = f2bf_rne(v - bf2f(h16));
                }
            }
        }
        const int arr = col & 3, aj = col >> 2;   // A-row a=col encodes (j, rr)
        const unsigned int* xsrc = h0 + ((size_t)(row0 + arr) * TT + aj) * 128 + 8 * rg;

        bf16x8 xA[8], xB[8];
        auto loadx = [&](int tbase, bf16x8 (&xr)[8]) {
            const unsigned int* p = xsrc + (size_t)tbase * 128;
#pragma unroll
            for (int ks = 0; ks < 4; ++ks) {
                const u32x4 a0 = *(const u32x4*)&p[ks * 32];
                const u32x4 a1 = *(const u32x4*)&p[ks * 32 + 4];
                u32x4 hw = {(a0[0] & 0xffffu) | (a0[1] << 16), (a0[2] & 0xffffu) | (a0[3] << 16),
                            (a1[0] & 0xffffu) | (a1[1] << 16), (a1[2] & 0xffffu) | (a1[3] << 16)};
                u32x4 lw = {(a0[0] >> 16) | (a0[1] & 0xffff0000u), (a0[2] >> 16) | (a0[3] & 0xffff0000u),
                            (a1[0] >> 16) | (a1[1] & 0xffff0000u), (a1[2] >> 16) | (a1[3] & 0xffff0000u)};
                xr[ks]     = __builtin_bit_cast(bf16x8, hw);
                xr[4 + ks] = __builtin_bit_cast(bf16x8, lw);
            }
        };
        auto ih_q = [&](int q, const bf16x8 (&xr)[8], int buf) {
            f32x4 a = {0.f, 0.f, 0.f, 0.f};
#pragma unroll
            for (int ks = 0; ks < 4; ++ks) {
                a = MFMA16(xr[ks],     wf_hi[q][ks], a);
                a = MFMA16(xr[4 + ks], wf_hi[q][ks], a);
                a = MFMA16(xr[ks],     wf_lo[q][ks], a);
            }
            a += bbq[q];                       // bias folded here (compute is bias-free)
            const int mq = m + 4 * q;
            const int ug = (mq & 3) * 16 + col, gi = mq >> 2;
            *(f32x4*)&ihaccf[((buf * 4 + rg) * 64 + ug) * 20 + gi * 4] = a;
        };

        loadx(0, xA);
        ih_q(0, xA, 0); ih_q(1, xA, 0); ih_q(2, xA, 0); ih_q(3, xA, 0);
        loadx(4, xB);
        __syncthreads();

        for (int tb = 0; tb < TT; tb += 8) {
            if (tb + 8 < TT) loadx(tb + 8, xA);
            ih_q(0, xB, 1); __syncthreads();
            ih_q(1, xB, 1); __syncthreads();
            ih_q(2, xB, 1); __syncthreads();
            ih_q(3, xB, 1); __syncthreads();
            if (tb + 12 < TT) loadx(tb + 12, xB);
            const bool doih = (tb + 8 < TT);
            if (doih) ih_q(0, xA, 0);
            __syncthreads();
            if (doih) ih_q(1, xA, 0);
            __syncthreads();
            if (doih) ih_q(2, xA, 0);
            __syncthreads();
            if (doih) ih_q(3, xA, 0);
            __syncthreads();
        }
    } else {
        // ======================= COMPUTE =======================
        const int w = W - 4;
        const int u = w * 16 + col;

        bf16x8 whh_hi[4][2], whh_lo[4][2];
#pragma unroll
        for (int q = 0; q < 4; ++q) {
            const int gate = (w + 4 * q) * 16 + col;
#pragma unroll
            for (int ks = 0; ks < 2; ++ks) {
                const float* src = w_hh + gate * HH + ks * 32 + 8 * rg;
#pragma unroll
                for (int e = 0; e < 8; ++e) {
                    float v = src[e];
                    short h16 = f2bf_rne(v);
                    whh_hi[q][ks][e] = h16;
                    whh_lo[q][ks][e] = f2bf_rne(v - bf2f(h16));
                }
            }
        }

        f32x4 cc = {0.f, 0.f, 0.f, 0.f};
        __syncthreads();

        auto step = [&](int t, int k) {
            const int cur = k & 1, nxt = cur ^ 1;
            const int j = k & 3, ib = k >> 2;
            f32x4 iv0, iv1, iv2, iv3;
            if (rg == 0) {
                const float* ibase = &ihaccf[((ib * 4 + j) * 64 + u) * 20];
                iv0 = *(const f32x4*)&ibase[0];
                iv1 = *(const f32x4*)&ibase[4];
                iv2 = *(const f32x4*)&ibase[8];
                iv3 = *(const f32x4*)&ibase[12];
            }
            const short* hb = &hsf[cur][0];
            bf16x8 ah0 = *(const bf16x8*)&hb[0 * 512 + l * 8];
            bf16x8 ah1 = *(const bf16x8*)&hb[1 * 512 + l * 8];
            bf16x8 ah2 = *(const bf16x8*)&hb[2 * 512 + l * 8];
            bf16x8 ah3 = *(const bf16x8*)&hb[3 * 512 + l * 8];
            f32x4 acc[4];
#pragma unroll
            for (int q = 0; q < 4; ++q) {
                f32x4 a = {0.f, 0.f, 0.f, 0.f};
                a = MFMA16(ah0, whh_hi[q][0], a);
                a = MFMA16(ah1, whh_hi[q][1], a);
                a = MFMA16(ah2, whh_hi[q][0], a);
                a = MFMA16(ah3, whh_hi[q][1], a);
                a = MFMA16(ah0, whh_lo[q][0], a);
                a = MFMA16(ah1, whh_lo[q][1], a);
                acc[q] = a;
            }
            if (rg == 0) {
#pragma unroll
                for (int r = 0; r < 4; ++r) {
                    const float gi_ = acc[0][r] + iv0[r];
                    const float gf_ = acc[1][r] + iv1[r];
                    const float gg_ = acc[2][r] + iv2[r];
                    const float go_ = acc[3][r] + iv3[r];
                    const float cn = sigf(gf_) * cc[r] + sigf(gi_) * tanh_fast(gg_);
                    const float hn = sigf(go_) * tanh_fast(cn);
                    cc[r] = cn;
                    const short hi16 = f2bf_rne(hn);
                    const int wa = hsf_waddr(u, r);
                    hsf[nxt][wa]        = hi16;
                    hsf[nxt][wa + 1024] = f2bf_rne(hn - bf2f(hi16));
                    if (t == TT - 1) h_last[(size_t)(row0 + r) * HH + u] = hn;
                }
            }
            __syncthreads();
        };

        for (int tb = 0; tb < TT; tb += 8) {
#pragma unroll
            for (int k = 0; k < 8; ++k) step(tb + k, k);
        }
    }
}

// ---------------------------------------------------------------------------
// Tail: layer-1 backward is ONE step at t=T-1 from zero state, then FC.
// Packed-u32 input.
// ---------------------------------------------------------------------------
__global__ void lstm_tail(const unsigned int* __restrict__ in0,
                          const float* __restrict__ h1f,
                          const float* __restrict__ w_ih_r,
                          const float* __restrict__ b_ih_r, const float* __restrict__ b_hh_r,
                          const float* __restrict__ fc_w, const float* __restrict__ fc_b,
                          float* __restrict__ out) {
    const int b   = blockIdx.x;
    const int tid = threadIdx.x;
    __shared__ __align__(16) float insl[DD1];
    __shared__ __align__(16) float hb[HH];
    __shared__ __align__(16) float gsh[256];

    if (tid < DD1) {
        const unsigned int v = in0[((size_t)b * TT + (TT - 1)) * 128 + tid];
        insl[tid] = bf2f((short)(v & 0xffffu)) + bf2f((short)(v >> 16));
    }
    __syncthreads();

    float a0 = b_ih_r[tid] + b_hh_r[tid], a1 = 0.f, a2 = 0.f, a3 = 0.f;
    const float4* in4 = (const float4*)insl;
#pragma unroll
    for (int kk = 0; kk < 32; ++kk) {
        float4 iv = in4[kk];
        float4 wv = *(const float4*)&w_ih_r[tid * DD1 + 4 * kk];
        a0 += wv.x * iv.x;
        a1 += wv.y * iv.y;
        a2 += wv.z * iv.z;
        a3 += wv.w * iv.w;
    }
    gsh[tid] = (a0 + a1) + (a2 + a3);
    __syncthreads();

    if (tid < HH) {
        const float gi = gsh[tid], gc = gsh[tid + 128], go = gsh[tid + 192];
        const float ccv = sigf(gi) * tanh_fast(gc);  // c_prev = 0
        hb[tid] = sigf(go) * tanh_fast(ccv);
    }
    __syncthreads();

    if (tid < 64) {
        float p = fc_w[tid] * h1f[(size_t)b * HH + tid] + fc_w[HH + tid] * hb[tid];
#pragma unroll
        for (int off = 32; off; off >>= 1) p += __shfl_xor(p, off);
        if (tid == 0) out[b] = p + fc_b[0];
    }
}

// ---------------------------------------------------------------------------
extern "C" void kernel_launch(void* const* d_in, const int* in_sizes, int n_in,
                              void* d_out, int out_size, void* d_ws, size_t ws_size,
                              hipStream_t stream) {
    const float* x = (const float*)d_in[0];
    // l0 fwd: 1..4, l0 rev: 5..8, l1 fwd: 9..12, l1 rev: 13..16, fc: 17,18
    char* ws = (char*)d_ws;
    const size_t out0_b = (size_t)NB * TT * 128 * 4;  // 134.2 MB packed u32

    unsigned int* out0 = (unsigned int*)ws;
    float* h1f = (float*)(ws + out0_b);

    lstm_l0<<<256, 256, 0, stream>>>(
        x, (const float*)d_in[1], (const float*)d_in[2], (const float*)d_in[3], (const float*)d_in[4],
        (const float*)d_in[5], (const float*)d_in[6], (const float*)d_in[7], (const float*)d_in[8], out0);
    lstm_l1_pc<<<256, 512, 0, stream>>>(
        out0, (const float*)d_in[9], (const float*)d_in[10], (const float*)d_in[11],
        (const float*)d_in[12], h1f);
    lstm_tail<<<1024, 256, 0, stream>>>(
        out0, h1f, (const float*)d_in[13], (const float*)d_in[15], (const float*)d_in[16],
        (const float*)d_in[17], (const float*)d_in[18], (float*)d_out);
}